// Round 10
// baseline (354.108 us; speedup 1.0000x reference)
//
#include <hip/hip_runtime.h>
#include <hip/hip_bf16.h>
#include <math.h>

#define B_ 8
#define P_ 24
#define N_ 1024
#define C_ 16
#define D_ 256
#define K_ 13

// workspace offsets (in floats)
#define OFF_SM   0          // spatial_mean: 192*16
#define OFF_DL   4096       // d_lag: 8*4*24
#define OFF_ATT  8192       // att: 8*24
#define OFF_GAM  9216       // gamma: 8*32 (re[13] @ +0, im[13] @ +16)
#define OFF_TE   12288      // te_fold: 192*256
#define OFF_FTR  65536      // Fte_re: 8*13*256
#define OFF_FTI  94208      // Fte_im
#define OFF_ZWC  122880     // zw_const: 8*256
#define OFF_AB   126976     // ABt bf16 [k][o][32]: 13*256*32 ushorts
#define OFF_BC   266240     // bias_comb: 13*256
#define OFF_DD   270336     // Dt bf16 [k][q][i]: 13*256*256 ushorts
#define OFF_W2E  696320     // W2ext bf16 [q2][288]
#define OFF_XC   1126400    // Xhat bf16 [b][k][n][32]: 8*13*1024*32 ushorts
#define OFF_XW   2830336    // xw fp32: 8*1024*16
#define OFF_ABP  3000000    // AB partials fp32 [k][et][32ch][256o]
#define OFF_C1P  3900000    // c1 partials fp32 [b][k][8ec][256]
#define OFF_PACC 4194304    // GEMM1 split-k partials fp32 [kh 3][b][n][q]: 3*8*1024*256

typedef unsigned short ushort_t;
typedef __bf16 bf16x8 __attribute__((ext_vector_type(8)));
typedef float f32x4 __attribute__((ext_vector_type(4)));
typedef unsigned short ushort4_t __attribute__((ext_vector_type(4)));

__device__ __forceinline__ float gelu_f(float v) {
    return 0.5f * v * (1.0f + erff(v * 0.70710678118654752440f));
}
__device__ __forceinline__ float softplus_f(float z) {
    return fmaxf(z, 0.0f) + log1pf(expf(-fabsf(z)));
}
__device__ __forceinline__ ushort_t f2bf(float f) {
    union { float f; unsigned u; } v; v.f = f;
    unsigned r = v.u + 0x7fffu + ((v.u >> 16) & 1u);
    return (ushort_t)(r >> 16);
}
__device__ __forceinline__ float bf2f(ushort_t h) {
    union { unsigned u; float f; } v; v.u = ((unsigned)h) << 16;
    return v.f;
}
__device__ __forceinline__ float4 f4add(float4 a, float4 b) {
    a.x += b.x; a.y += b.y; a.z += b.z; a.w += b.w; return a;
}
__device__ __forceinline__ ushort4_t pack4(f32x4 v, float4 c) {
    ushort4_t w;
    w.x = f2bf(gelu_f(v[0] + c.x));
    w.y = f2bf(gelu_f(v[1] + c.y));
    w.z = f2bf(gelu_f(v[2] + c.z));
    w.w = f2bf(gelu_f(v[3] + c.w));
    return w;
}
__device__ __forceinline__ ushort4_t pack4f(float4 v, float4 c) {
    ushort4_t w;
    w.x = f2bf(gelu_f(v.x + c.x));
    w.y = f2bf(gelu_f(v.y + c.y));
    w.z = f2bf(gelu_f(v.z + c.z));
    w.w = f2bf(gelu_f(v.w + c.w));
    return w;
}

// ==== stage1: spatial_mean(192) + lag_dist(192) + xhat-DFT(512), 256 thr ====
__global__ void k_stage1(const float* __restrict__ x, float* __restrict__ ws) {
    __shared__ __align__(16) char smem[4096];
    int bx = blockIdx.x, tid = threadIdx.x;
    if (bx < 192) {
        float* lds = (float*)smem;
        int bt = bx;
        int c = tid & 15, ns = tid >> 4;
        const float* xp = x + (long)bt * (N_ * C_);
        float s = 0.f;
        for (int n = ns; n < N_; n += 16) s += xp[n * C_ + c];
        lds[tid] = s;
        __syncthreads();
        for (int st = 128; st >= 16; st >>= 1) {
            if (tid < st) lds[tid] += lds[tid + st];
            __syncthreads();
        }
        if (tid < 16) ws[OFF_SM + bt * 16 + tid] = lds[tid] * (1.0f / 1024.0f);
    } else if (bx < 384) {
        int j = bx - 192;
        int t = j % P_, b = j / P_;
        float4* red = (float4*)smem;
        const float* xp = x + (long)b * P_ * N_ * C_;
        float s1 = 0.f, s2 = 0.f, s4 = 0.f, s6 = 0.f;
        for (int idx = tid; idx < N_ * C_; idx += 256) {
            float xv[9];
            #pragma unroll
            for (int jj = 0; jj < 9; jj++)
                xv[jj] = (t - jj >= 0) ? xp[(long)(t - jj) * (N_ * C_) + idx] : 0.f;
            float xr[7];
            #pragma unroll
            for (int jj = 0; jj < 7; jj++) {
                int s = t - jj;
                float xt = xv[jj];
                xr[jj] = (s <= 0) ? 0.f
                       : (s == 1) ? (xt - xv[jj + 1])
                       : (xt - (xt + xv[jj + 1] + xv[jj + 2]) * (1.0f / 3.0f));
            }
            if (t >= 1) s1 += fabsf(xr[0] - xr[1]);
            if (t >= 2) s2 += fabsf(xr[0] - xr[2]);
            if (t >= 4) s4 += fabsf(xr[0] - xr[4]);
            if (t >= 6) s6 += fabsf(xr[0] - xr[6]);
        }
        red[tid] = make_float4(s1, s2, s4, s6);
        __syncthreads();
        for (int st = 128; st > 0; st >>= 1) {
            if (tid < st) red[tid] = f4add(red[tid], red[tid + st]);
            __syncthreads();
        }
        if (tid == 0) {
            const float inv = 1.0f / (N_ * C_);
            ws[OFF_DL + (b * 4 + 0) * P_ + t] = red[0].x * inv;
            ws[OFF_DL + (b * 4 + 1) * P_ + t] = red[0].y * inv;
            ws[OFF_DL + (b * 4 + 2) * P_ + t] = red[0].z * inv;
            ws[OFF_DL + (b * 4 + 3) * P_ + t] = red[0].w * inv;
        }
    } else {
        int j = bx - 384;
        int ntile = j & 63, b = j >> 6;
        float* ct = (float*)smem;
        float* st = ct + K_ * P_;
        int n = ntile * 16 + (tid >> 4), c = tid & 15;
        for (int i = tid; i < K_ * P_; i += 256) {
            int k = i / P_, t = i % P_;
            int r = (k * t) % P_;
            float ph = 6.283185307179586f * (float)r / (float)P_;
            ct[i] = cosf(ph);
            st[i] = sinf(ph);
        }
        __syncthreads();
        float re[K_], im[K_];
        #pragma unroll
        for (int k = 0; k < K_; k++) { re[k] = 0.f; im[k] = 0.f; }
        for (int t = 0; t < P_; t++) {
            float v = x[((long)(b * P_ + t) * N_ + n) * C_ + c];
            #pragma unroll
            for (int k = 0; k < K_; k++) {
                re[k] += ct[k * P_ + t] * v;
                im[k] -= st[k * P_ + t] * v;
            }
        }
        ushort_t* xcp = (ushort_t*)(ws + OFF_XC);
        #pragma unroll
        for (int k = 0; k < K_; k++) {
            long xb = ((long)(b * K_ + k) * N_ + n) * 32;
            xcp[xb + c] = f2bf(re[k]);
            xcp[xb + 16 + c] = f2bf(im[k]);
        }
    }
}

// ==== stage2: gating+gamma (8 blocks) + time_emb (192 blocks), 128 thr ====
__global__ void k_stage2(const float* __restrict__ pool_param,
                         const float* __restrict__ pe_w1, const float* __restrict__ pe_b1,
                         const float* __restrict__ pe_w2, const float* __restrict__ pe_b2,
                         const float* __restrict__ noise_w, const float* __restrict__ noise_b,
                         const float* __restrict__ in_proj_b, float* __restrict__ ws) {
    __shared__ float sm[256];
    int bx = blockIdx.x, tid = threadIdx.x;
    if (bx < 8) {
        int b = bx;
        float* d = sm; float* ad = sm + 96; float* med = sm + 192; float* mad = sm + 196;
        float* attb = sm + 200; float* gbuf = sm + 224;
        int li = tid / P_, t = tid - li * P_;
        bool active = tid < 4 * P_;
        if (active) d[li * P_ + t] = ws[OFF_DL + (b * 4 + li) * P_ + t];
        __syncthreads();
        if (active) {
            float v = d[li * P_ + t];
            int rank = 0;
            #pragma unroll
            for (int jj = 0; jj < P_; jj++) {
                float dj = d[li * P_ + jj];
                rank += (dj < v || (dj == v && jj < t)) ? 1 : 0;
            }
            if (rank == 11) med[li] = v;
        }
        __syncthreads();
        if (active) ad[li * P_ + t] = fabsf(d[li * P_ + t] - med[li]);
        __syncthreads();
        if (active) {
            float v = ad[li * P_ + t];
            int rank = 0;
            #pragma unroll
            for (int jj = 0; jj < P_; jj++) {
                float dj = ad[li * P_ + jj];
                rank += (dj < v || (dj == v && jj < t)) ? 1 : 0;
            }
            if (rank == 11) mad[li] = v;
        }
        __syncthreads();
        if (active) {
            float z = (d[li * P_ + t] - med[li]) / (mad[li] * 1.4826f + 1e-6f);
            ad[li * P_ + t] = softplus_f(z);
        }
        __syncthreads();
        if (tid == 0) {
            float g[P_];
            #pragma unroll
            for (int tt = 0; tt < P_; tt++)
                g[tt] = 0.25f * (ad[tt] + ad[P_ + tt] + ad[2 * P_ + tt] + ad[3 * P_ + tt]);
            float c = g[0];
            gbuf[0] = g[0];
            for (int tt = 1; tt < P_; tt++) { c = 0.6f * c + 0.4f * g[tt]; gbuf[tt] = c; }
            float mean = 0.f;
            for (int tt = 0; tt < P_; tt++) mean += gbuf[tt];
            mean *= (1.0f / P_);
            float gate[P_];
            #pragma unroll
            for (int tt = 0; tt < P_; tt++) gate[tt] = 1.0f / (1.0f + expf(-1.5f * (gbuf[tt] - mean)));
            float m = -1e30f;
            float pp[P_];
            #pragma unroll
            for (int tt = 0; tt < P_; tt++) { pp[tt] = pool_param[tt]; m = fmaxf(m, pp[tt]); }
            float ssum = 0.f;
            #pragma unroll
            for (int tt = 0; tt < P_; tt++) { pp[tt] = expf(pp[tt] - m); ssum += pp[tt]; }
            float m2 = -1e30f;
            #pragma unroll
            for (int tt = 0; tt < P_; tt++) { pp[tt] = (pp[tt] / ssum) * (1.0f + gate[tt]); m2 = fmaxf(m2, pp[tt]); }
            float s2 = 0.f;
            #pragma unroll
            for (int tt = 0; tt < P_; tt++) { pp[tt] = expf(pp[tt] - m2); s2 += pp[tt]; }
            #pragma unroll
            for (int tt = 0; tt < P_; tt++) {
                float a = pp[tt] / s2;
                ws[OFF_ATT + b * P_ + tt] = a;
                attb[tt] = a;
            }
        }
        __syncthreads();
        if (tid < K_) {
            int k = tid;
            float cre = 0.f, cim = 0.f;
            for (int t2 = 0; t2 < P_; t2++) {
                int r = (k * t2) % P_;
                float ph = 6.283185307179586f * (float)r / (float)P_;
                float a = attb[t2];
                cre += a * cosf(ph);
                cim += a * sinf(ph);
            }
            float w = (k == 0 || k == 12) ? 1.0f : 2.0f;
            ws[OFF_GAM + b * 32 + k] = (w / 24.0f) * cre;
            ws[OFF_GAM + b * 32 + 16 + k] = -(w / 24.0f) * cim;
        }
    } else {
        int bt = bx - 8;
        int t = bt % P_;
        int k = tid >> 6, o = tid & 63;
        float* p1e = sm;
        float period = (k == 0) ? 24.0f : 72.0f;
        float ph = 6.283185307179586f * (float)t / period;
        float sv = sinf(ph), cv = cosf(ph);
        float v = sv * pe_w1[(k * 2 + 0) * 64 + o] + cv * pe_w1[(k * 2 + 1) * 64 + o] + pe_b1[k * 64 + o];
        p1e[tid] = gelu_f(v);
        __syncthreads();
        float acc = pe_b2[k * 64 + o];
        for (int i = 0; i < 64; i++) acc += p1e[k * 64 + i] * pe_w2[(k * 64 + i) * 64 + o];
        ws[OFF_TE + bt * D_ + tid] = acc + in_proj_b[tid];
        float nacc = noise_b[tid];
        for (int c = 0; c < C_; c++) nacc += ws[OFF_SM + bt * C_ + c] * noise_w[c * 128 + tid];
        ws[OFF_TE + bt * D_ + 128 + tid] = nacc + in_proj_b[128 + tid];
    }
}

// ==== stage3: te_reduce(8) + ab_part(104) + prep_d(208) + prep_w2(256), 256 thr ====
__global__ void k_stage3(const float* __restrict__ in_proj_b, const float* __restrict__ in_proj_w,
                         const float* __restrict__ sfe_w1, const float* __restrict__ sfe_w2,
                         const float* __restrict__ sfe_b2, const float* __restrict__ comb_w1,
                         const float* __restrict__ comb_w2,
                         float* __restrict__ ws, float* __restrict__ out) {
    __shared__ __align__(16) char smem[16640];
    int bx = blockIdx.x, tid = threadIdx.x;
    if (bx < 8) {
        int b = bx;
        float* ct = (float*)smem;
        float* st = ct + K_ * P_;
        float* attl = st + K_ * P_;
        for (int i = tid; i < K_ * P_; i += 256) {
            int k = i / P_, t = i % P_;
            int r = (k * t) % P_;
            float ph = 6.283185307179586f * (float)r / (float)P_;
            ct[i] = cosf(ph);
            st[i] = sinf(ph);
        }
        if (tid < P_) attl[tid] = ws[OFF_ATT + b * P_ + tid];
        __syncthreads();
        float fre[K_], fim[K_];
        #pragma unroll
        for (int k = 0; k < K_; k++) { fre[k] = 0.f; fim[k] = 0.f; }
        float smn = 0.f, sa = 0.f;
        for (int t = 0; t < P_; t++) {
            float v = ws[OFF_TE + (b * P_ + t) * D_ + tid];
            smn += v;
            sa += attl[t] * v;
            #pragma unroll
            for (int k = 0; k < K_; k++) {
                fre[k] += ct[k * P_ + t] * v;
                fim[k] -= st[k * P_ + t] * v;
            }
        }
        out[2097152 + b * D_ + tid] = smn * (1.0f / P_) - in_proj_b[tid];
        ws[OFF_ZWC + b * D_ + tid] = sa;
        #pragma unroll
        for (int k = 0; k < K_; k++) {
            ws[OFF_FTR + (b * K_ + k) * D_ + tid] = fre[k];
            ws[OFF_FTI + (b * K_ + k) * D_ + tid] = fim[k];
        }
    } else if (bx < 112) {
        int j = bx - 8;
        int k = j >> 3, et = j & 7;
        int o = tid;
        float accA[C_], accB[C_];
        #pragma unroll
        for (int c = 0; c < C_; c++) { accA[c] = 0.f; accB[c] = 0.f; }
        const float* w1r = sfe_w1 + (long)k * 512 * 256;
        const float* w1i = w1r + 256 * 256;
        for (int e = et * 32; e < et * 32 + 32; e++) {
            float vr = w1r[e * 256 + o];
            float vi = w1i[e * 256 + o];
            #pragma unroll
            for (int c = 0; c < C_; c++) {
                float w = in_proj_w[c * 256 + e];
                accA[c] += w * vr;
                accB[c] += w * vi;
            }
        }
        float* abp = ws + OFF_ABP + (long)((k * 8 + et) * 32) * 256;
        #pragma unroll
        for (int c = 0; c < C_; c++) {
            abp[c * 256 + o] = accA[c];
            abp[(16 + c) * 256 + o] = accB[c];
        }
    } else if (bx < 320) {
        int j = bx - 112;
        int qt0 = (j & 3) * 64, it0 = ((j >> 2) & 3) * 64, k = j >> 4;
        float* As = (float*)smem;        // 64*33
        float* Bs = As + 64 * 33;        // 32*64
        int tq = tid & 15, ti = tid >> 4;
        float acc[4][4];
        #pragma unroll
        for (int r = 0; r < 4; r++)
            #pragma unroll
            for (int c = 0; c < 4; c++) acc[r][c] = 0.f;
        float bias = 0.f;
        for (int step = 0; step < 8; step++) {
            int ob = step * 32;
            __syncthreads();
            #pragma unroll
            for (int u = 0; u < 8; u++) {
                int idx = u * 256 + tid;
                int i = idx >> 5, o = idx & 31;
                As[i * 33 + o] = sfe_w2[((long)(k * 256 + it0 + i) << 8) + ob + o];
            }
            #pragma unroll
            for (int u = 0; u < 8; u++) {
                int idx = u * 256 + tid;
                int o = idx >> 6, q = idx & 63;
                Bs[o * 64 + q] = comb_w1[((long)(k * 256 + ob + o) << 8) + qt0 + q];
            }
            __syncthreads();
            if (it0 == 0 && tid < 64) {
                #pragma unroll
                for (int o = 0; o < 32; o++)
                    bias += sfe_b2[k * 256 + ob + o] * Bs[o * 64 + tid];
            }
            #pragma unroll 4
            for (int o = 0; o < 32; o++) {
                const float4 bv = *(const float4*)&Bs[o * 64 + tq * 4];
                float a[4];
                #pragma unroll
                for (int r = 0; r < 4; r++) a[r] = As[(ti * 4 + r) * 33 + o];
                #pragma unroll
                for (int r = 0; r < 4; r++) {
                    acc[r][0] += a[r] * bv.x;
                    acc[r][1] += a[r] * bv.y;
                    acc[r][2] += a[r] * bv.z;
                    acc[r][3] += a[r] * bv.w;
                }
            }
        }
        ushort_t* dtp = (ushort_t*)(ws + OFF_DD);
        #pragma unroll
        for (int c = 0; c < 4; c++)
            #pragma unroll
            for (int r = 0; r < 4; r++)
                dtp[((k * 256 + qt0 + tq * 4 + c) << 8) + it0 + ti * 4 + r] = f2bf(acc[r][c]);
        if (it0 == 0 && tid < 64)
            ws[OFF_BC + k * 256 + qt0 + tid] = bias;
    } else {
        int q2 = bx - 320;
        ushort_t* w2e = (ushort_t*)(ws + OFF_W2E);
        for (int i = tid; i < 288; i += 256) {
            float v = 0.f;
            if (i < 256) v = comb_w2[(i << 8) + q2];
            else if (i < 272) v = in_proj_w[((i - 256) << 8) + q2] * (1.0f / 0.3f);
            w2e[q2 * 288 + i] = f2bf(v);
        }
    }
}

// ==== stage4: ab_red(13) + c1(104) + xw-from-Xhat(512), 256 thr ====
__global__ void k_stage4(const float* __restrict__ sfe_w1, const float* __restrict__ sfe_b1,
                         float* __restrict__ ws) {
    __shared__ __align__(16) char smem[2608];
    int bx = blockIdx.x, tid = threadIdx.x;
    if (bx < 13) {
        int k = bx, o = tid;
        ushort_t* abt = (ushort_t*)(ws + OFF_AB);
        const float* base = ws + OFF_ABP + (long)(k * 8 * 32) * 256;
        #pragma unroll
        for (int ch = 0; ch < 32; ch++) {
            float s = 0.f;
            #pragma unroll
            for (int et = 0; et < 8; et++) s += base[(et * 32 + ch) * 256 + o];
            abt[(k * 256 + o) * 32 + ch] = f2bf(s);
        }
    } else if (bx < 117) {
        int j = bx - 13;
        int k = j >> 3, ec = j & 7;
        float* F = (float*)smem;  // [8b][64c]
        for (int i = tid; i < 512; i += 256) {
            int bb = i >> 6, cc = i & 63;
            int cg = ec * 64 + cc;
            F[i] = (cg < 256) ? ws[OFF_FTR + (bb * K_ + k) * D_ + cg]
                              : ws[OFF_FTI + (bb * K_ + k) * D_ + cg - 256];
        }
        __syncthreads();
        int o = tid;
        float acc[8];
        float b1 = (ec == 0) ? sfe_b1[k * 256 + o] : 0.f;
        #pragma unroll
        for (int bb = 0; bb < 8; bb++) acc[bb] = b1;
        const float* w1 = sfe_w1 + (long)k * 512 * 256 + (long)(ec * 64) * 256;
        for (int c = 0; c < 64; c++) {
            float w = w1[c * 256 + o];
            #pragma unroll
            for (int bb = 0; bb < 8; bb++) acc[bb] += F[bb * 64 + c] * w;
        }
        #pragma unroll
        for (int bb = 0; bb < 8; bb++)
            ws[OFF_C1P + (long)(((bb * K_ + k) * 8) + ec) * 256 + o] = acc[bb];
    } else {
        int j = bx - 117;
        int ntile = j & 63, b = j >> 6;
        int n = ntile * 16 + (tid >> 4), c = tid & 15;
        float gre[K_], gim[K_];
        #pragma unroll
        for (int k = 0; k < K_; k++) {
            gre[k] = ws[OFF_GAM + b * 32 + k];
            gim[k] = ws[OFF_GAM + b * 32 + 16 + k];
        }
        const ushort_t* xcp = (const ushort_t*)(ws + OFF_XC);
        float acc = 0.f;
        #pragma unroll
        for (int k = 0; k < K_; k++) {
            long xb = ((long)(b * K_ + k) * N_ + n) * 32;
            acc += gre[k] * bf2f(xcp[xb + c]) + gim[k] * bf2f(xcp[xb + 16 + c]);
        }
        ws[OFF_XW + ((long)b * N_ + n) * C_ + c] = acc;
    }
}

// pack-stage for one k: c1 loads + p-MFMA + gelu-pack (no LDS access)
__device__ __forceinline__ void pack_stage(
        const float* __restrict__ ws, const ushort_t* __restrict__ xch,
        const ushort_t* __restrict__ abt, int b, int kk, int n0,
        int l15, int quad, int wq0, int oc0, int oc1, ushort4_t* w) {
    long xb = ((long)(b * K_ + kk) * N_ + n0) * 32;
    bf16x8 pa0 = *(const bf16x8*)&xch[xb + l15 * 32 + quad * 8];
    bf16x8 pa1 = *(const bf16x8*)&xch[xb + (16 + l15) * 32 + quad * 8];
    const ushort_t* ab = abt + (kk * 256 + wq0 + l15) * 32 + quad * 8;
    bf16x8 pb0 = *(const bf16x8*)ab;
    bf16x8 pb1 = *(const bf16x8*)(ab + 16 * 32);
    float4 c10 = make_float4(0.f, 0.f, 0.f, 0.f), c11 = c10;
    #pragma unroll
    for (int ec = 0; ec < 8; ec++) {
        const float* cp = ws + OFF_C1P + (long)(((b * K_ + kk) * 8) + ec) * 256;
        c10 = f4add(c10, *(const float4*)&cp[oc0]);
        c11 = f4add(c11, *(const float4*)&cp[oc1]);
    }
    f32x4 p00 = {}, p01 = {}, p10 = {}, p11 = {};
    p00 = __builtin_amdgcn_mfma_f32_16x16x32_bf16(pb0, pa0, p00, 0, 0, 0);
    p01 = __builtin_amdgcn_mfma_f32_16x16x32_bf16(pb0, pa1, p01, 0, 0, 0);
    p10 = __builtin_amdgcn_mfma_f32_16x16x32_bf16(pb1, pa0, p10, 0, 0, 0);
    p11 = __builtin_amdgcn_mfma_f32_16x16x32_bf16(pb1, pa1, p11, 0, 0, 0);
    w[0] = pack4(p00, c10);
    w[1] = pack4(p01, c10);
    w[2] = pack4(p10, c11);
    w[3] = pack4(p11, c11);
}

// ==== k_final1: split-k(3) GEMM1 partial, 32n tile, SINGLE 16.9KB slab ====
// Scheduler LDS pool is ~64KB/CU (R7/R8/R9 occupancy evidence): 3*16896=50.7KB
// -> 3 blocks/CU co-resident. launch_bounds(512,6) caps VGPR at ~85 (body
// needs ~76-80 per R9 compile). 2 barriers/k; pack-stage(k+1) hoisted between
// barrier and s-loop so it overlaps GEMM1.
__global__ __launch_bounds__(512, 6) void k_final1(
        const float* __restrict__ ws, const ushort_t* __restrict__ xch,
        const ushort_t* __restrict__ abt, float* __restrict__ pacc) {
    int ntile = blockIdx.x, b = blockIdx.y, kh = blockIdx.z;
    int n0 = ntile * 32;
    const int k0 = (kh == 0) ? 0 : (kh == 1) ? 5 : 9;
    const int k1 = (kh == 0) ? 5 : (kh == 1) ? 9 : 13;
    int tid = threadIdx.x;
    int lane = tid & 63, wave = tid >> 6;
    int l15 = lane & 15, quad = lane >> 4;
    int wq0 = wave * 32;
    __shared__ ushort_t sl[32 * 264];    // 16896 B
    const ushort_t* dt = (const ushort_t*)(ws + OFF_DD);
    int oc0 = wq0 + quad * 4, oc1 = oc0 + 16;
    f32x4 a00 = {}, a01 = {}, a10 = {}, a11 = {};
    ushort4_t w[4];
    pack_stage(ws, xch, abt, b, k0, n0, l15, quad, wq0, oc0, oc1, w);
    for (int k = k0; k < k1; k++) {
        __syncthreads();   // all reads of sl from k-1 complete
        *(ushort4_t*)&sl[l15 * 264 + oc0] = w[0];
        *(ushort4_t*)&sl[(16 + l15) * 264 + oc0] = w[1];
        *(ushort4_t*)&sl[l15 * 264 + oc1] = w[2];
        *(ushort4_t*)&sl[(16 + l15) * 264 + oc1] = w[3];
        __syncthreads();   // writes visible
        if (k + 1 < k1)
            pack_stage(ws, xch, abt, b, k + 1, n0, l15, quad, wq0, oc0, oc1, w);
        // GEMM1 swapped: D[q'][n] = dt x slab^T
        const ushort_t* dbase = dt + (((long)(k * 256 + wq0 + l15)) << 8);
        #pragma unroll
        for (int s = 0; s < 8; s++) {
            int i0 = s * 32 + quad * 8;
            bf16x8 A0 = *(const bf16x8*)(dbase + i0);
            bf16x8 A1 = *(const bf16x8*)(dbase + (16 << 8) + i0);
            bf16x8 B0 = *(const bf16x8*)&sl[l15 * 264 + i0];
            bf16x8 B1 = *(const bf16x8*)&sl[(16 + l15) * 264 + i0];
            a00 = __builtin_amdgcn_mfma_f32_16x16x32_bf16(A0, B0, a00, 0, 0, 0);
            a01 = __builtin_amdgcn_mfma_f32_16x16x32_bf16(A0, B1, a01, 0, 0, 0);
            a10 = __builtin_amdgcn_mfma_f32_16x16x32_bf16(A1, B0, a10, 0, 0, 0);
            a11 = __builtin_amdgcn_mfma_f32_16x16x32_bf16(A1, B1, a11, 0, 0, 0);
        }
    }
    float* pp = pacc + ((long)(kh * 8 + b) * N_ + n0) * 256;
    *(float4*)&pp[(l15 << 8) + oc0] = make_float4(a00[0], a00[1], a00[2], a00[3]);
    *(float4*)&pp[((16 + l15) << 8) + oc0] = make_float4(a01[0], a01[1], a01[2], a01[3]);
    *(float4*)&pp[(l15 << 8) + oc1] = make_float4(a10[0], a10[1], a10[2], a10[3]);
    *(float4*)&pp[((16 + l15) << 8) + oc1] = make_float4(a11[0], a11[1], a11[2], a11[3]);
}

// ==== k_final2: sum 3 partials -> bias+gelu -> GEMM2 -> z, 32n tile ====
__global__ __launch_bounds__(512, 2) void k_final2(
        const float* __restrict__ ws, const float* __restrict__ pacc,
        const float* __restrict__ comb_b1, const float* __restrict__ comb_b2,
        float* __restrict__ out) {
    int ntile = blockIdx.x, b = blockIdx.y;  // 32 x 8
    int n0 = ntile * 32;
    int tid = threadIdx.x;
    int lane = tid & 63, wave = tid >> 6;
    int l15 = lane & 15, quad = lane >> 4;
    int wq0 = wave * 32;
    __shared__ ushort_t sh2[32 * 296];
    const ushort_t* w2e = (const ushort_t*)(ws + OFF_W2E);
    int oc0 = wq0 + quad * 4, oc1 = oc0 + 16;
    const float* p0 = pacc + ((long)(0 * 8 + b) * N_ + n0) * 256;
    const float* p1 = pacc + ((long)(1 * 8 + b) * N_ + n0) * 256;
    const float* p2 = pacc + ((long)(2 * 8 + b) * N_ + n0) * 256;
    float4 s00 = f4add(f4add(*(const float4*)&p0[(l15 << 8) + oc0],
                             *(const float4*)&p1[(l15 << 8) + oc0]),
                       *(const float4*)&p2[(l15 << 8) + oc0]);
    float4 s01 = f4add(f4add(*(const float4*)&p0[((16 + l15) << 8) + oc0],
                             *(const float4*)&p1[((16 + l15) << 8) + oc0]),
                       *(const float4*)&p2[((16 + l15) << 8) + oc0]);
    float4 s10 = f4add(f4add(*(const float4*)&p0[(l15 << 8) + oc1],
                             *(const float4*)&p1[(l15 << 8) + oc1]),
                       *(const float4*)&p2[(l15 << 8) + oc1]);
    float4 s11 = f4add(f4add(*(const float4*)&p0[((16 + l15) << 8) + oc1],
                             *(const float4*)&p1[((16 + l15) << 8) + oc1]),
                       *(const float4*)&p2[((16 + l15) << 8) + oc1]);
    float4 bc0 = *(const float4*)&comb_b1[oc0];
    float4 bc1 = *(const float4*)&comb_b1[oc1];
    #pragma unroll
    for (int k = 0; k < K_; k++) {
        bc0 = f4add(bc0, *(const float4*)&ws[OFF_BC + k * 256 + oc0]);
        bc1 = f4add(bc1, *(const float4*)&ws[OFF_BC + k * 256 + oc1]);
    }
    *(ushort4_t*)&sh2[l15 * 296 + oc0]        = pack4f(s00, bc0);
    *(ushort4_t*)&sh2[(16 + l15) * 296 + oc0] = pack4f(s01, bc0);
    *(ushort4_t*)&sh2[l15 * 296 + oc1]        = pack4f(s10, bc1);
    *(ushort4_t*)&sh2[(16 + l15) * 296 + oc1] = pack4f(s11, bc1);
    {
        int row = tid >> 4, cc = tid & 15;  // 32 rows x 16 c
        float xv = ws[OFF_XW + ((long)b * N_ + n0 + row) * C_ + cc];
        sh2[row * 296 + 256 + cc] = f2bf(xv);
        sh2[row * 296 + 272 + cc] = 0;
    }
    __syncthreads();
    // GEMM2 swapped: D[q2][n] = w2e x Uext^T
    f32x4 h00 = {}, h01 = {}, h10 = {}, h11 = {};
    #pragma unroll
    for (int s = 0; s < 9; s++) {
        int i0 = s * 32 + quad * 8;
        bf16x8 A0 = *(const bf16x8*)&w2e[(wq0 + l15) * 288 + i0];
        bf16x8 A1 = *(const bf16x8*)&w2e[(wq0 + 16 + l15) * 288 + i0];
        bf16x8 B0 = *(const bf16x8*)&sh2[l15 * 296 + i0];
        bf16x8 B1 = *(const bf16x8*)&sh2[(16 + l15) * 296 + i0];
        h00 = __builtin_amdgcn_mfma_f32_16x16x32_bf16(A0, B0, h00, 0, 0, 0);
        h01 = __builtin_amdgcn_mfma_f32_16x16x32_bf16(A0, B1, h01, 0, 0, 0);
        h10 = __builtin_amdgcn_mfma_f32_16x16x32_bf16(A1, B0, h10, 0, 0, 0);
        h11 = __builtin_amdgcn_mfma_f32_16x16x32_bf16(A1, B1, h11, 0, 0, 0);
    }
    float4 zc0 = *(const float4*)&ws[OFF_ZWC + b * 256 + oc0];
    float4 zc1 = *(const float4*)&ws[OFF_ZWC + b * 256 + oc1];
    float4 cb0 = *(const float4*)&comb_b2[oc0];
    float4 cb1 = *(const float4*)&comb_b2[oc1];
    long ob = ((long)b * N_ + n0) << 8;
    float4 o00, o01, o10, o11;
    o00.x = zc0.x + 0.3f * (h00[0] + cb0.x); o00.y = zc0.y + 0.3f * (h00[1] + cb0.y);
    o00.z = zc0.z + 0.3f * (h00[2] + cb0.z); o00.w = zc0.w + 0.3f * (h00[3] + cb0.w);
    o01.x = zc0.x + 0.3f * (h01[0] + cb0.x); o01.y = zc0.y + 0.3f * (h01[1] + cb0.y);
    o01.z = zc0.z + 0.3f * (h01[2] + cb0.z); o01.w = zc0.w + 0.3f * (h01[3] + cb0.w);
    o10.x = zc1.x + 0.3f * (h10[0] + cb1.x); o10.y = zc1.y + 0.3f * (h10[1] + cb1.y);
    o10.z = zc1.z + 0.3f * (h10[2] + cb1.z); o10.w = zc1.w + 0.3f * (h10[3] + cb1.w);
    o11.x = zc1.x + 0.3f * (h11[0] + cb1.x); o11.y = zc1.y + 0.3f * (h11[1] + cb1.y);
    o11.z = zc1.z + 0.3f * (h11[2] + cb1.z); o11.w = zc1.w + 0.3f * (h11[3] + cb1.w);
    *(float4*)&out[ob + ((long)l15 << 8) + oc0] = o00;
    *(float4*)&out[ob + ((long)(16 + l15) << 8) + oc0] = o01;
    *(float4*)&out[ob + ((long)l15 << 8) + oc1] = o10;
    *(float4*)&out[ob + ((long)(16 + l15) << 8) + oc1] = o11;
}

extern "C" void kernel_launch(void* const* d_in, const int* in_sizes, int n_in,
                              void* d_out, int out_size, void* d_ws, size_t ws_size,
                              hipStream_t stream) {
    const float* x = (const float*)d_in[0];
    const float* in_proj_w = (const float*)d_in[1];
    const float* in_proj_b = (const float*)d_in[2];
    const float* pe_w1 = (const float*)d_in[3];
    const float* pe_b1 = (const float*)d_in[4];
    const float* pe_w2 = (const float*)d_in[5];
    const float* pe_b2 = (const float*)d_in[6];
    const float* noise_w = (const float*)d_in[7];
    const float* noise_b = (const float*)d_in[8];
    const float* sfe_w1 = (const float*)d_in[9];
    const float* sfe_b1 = (const float*)d_in[10];
    const float* sfe_w2 = (const float*)d_in[11];
    const float* sfe_b2 = (const float*)d_in[12];
    const float* comb_w1 = (const float*)d_in[13];
    const float* comb_b1 = (const float*)d_in[14];
    const float* comb_w2 = (const float*)d_in[15];
    const float* comb_b2 = (const float*)d_in[16];
    const float* pool_param = (const float*)d_in[17];
    float* ws = (float*)d_ws;
    float* out = (float*)d_out;

    hipLaunchKernelGGL(k_stage1, dim3(896), dim3(256), 0, stream, x, ws);
    hipLaunchKernelGGL(k_stage2, dim3(200), dim3(128), 0, stream,
                       pool_param, pe_w1, pe_b1, pe_w2, pe_b2, noise_w, noise_b, in_proj_b, ws);
    hipLaunchKernelGGL(k_stage3, dim3(576), dim3(256), 0, stream,
                       in_proj_b, in_proj_w, sfe_w1, sfe_w2, sfe_b2, comb_w1, comb_w2, ws, out);
    hipLaunchKernelGGL(k_stage4, dim3(629), dim3(256), 0, stream, sfe_w1, sfe_b1, ws);
    hipLaunchKernelGGL(k_final1, dim3(32, 8, 3), dim3(512), 0, stream,
                       ws, (const ushort_t*)(ws + OFF_XC), (const ushort_t*)(ws + OFF_AB),
                       ws + OFF_PACC);
    hipLaunchKernelGGL(k_final2, dim3(32, 8), dim3(512), 0, stream,
                       ws, ws + OFF_PACC, comb_b1, comb_b2, out);
}

// Round 11
// 273.959 us; speedup vs baseline: 1.2926x; 1.2926x over previous
//
#include <hip/hip_runtime.h>
#include <hip/hip_bf16.h>
#include <math.h>

#define B_ 8
#define P_ 24
#define N_ 1024
#define C_ 16
#define D_ 256
#define K_ 13

// workspace offsets (in floats)
#define OFF_SM   0          // spatial_mean: 192*16
#define OFF_DL   4096       // d_lag: 8*4*24
#define OFF_ATT  8192       // att: 8*24
#define OFF_GAM  9216       // gamma: 8*32 (re[13] @ +0, im[13] @ +16)
#define OFF_TE   12288      // te_fold: 192*256
#define OFF_FTR  65536      // Fte_re: 8*13*256
#define OFF_FTI  94208      // Fte_im
#define OFF_ZWC  122880     // zw_const: 8*256
#define OFF_AB   126976     // ABt bf16 [k][o][32]: 13*256*32 ushorts
#define OFF_BC   266240     // bias_comb: 13*256
#define OFF_DD   270336     // Dt bf16 [k][q][i]: 13*256*256 ushorts
#define OFF_W2E  696320     // W2ext bf16 [q2][288]
#define OFF_XC   1126400    // Xhat bf16 [b][k][n][32]: 8*13*1024*32 ushorts
#define OFF_XW   2830336    // xw fp32: 8*1024*16
#define OFF_ABP  3000000    // AB partials fp32 [k][et][32ch][256o]
#define OFF_C1P  3900000    // c1 partials fp32 [b][k][8ec][256]
#define OFF_PACC 4194304    // GEMM1 split-k partials fp32 [kh 2][b][n][q]: 2*8*1024*256

typedef unsigned short ushort_t;
typedef __bf16 bf16x8 __attribute__((ext_vector_type(8)));
typedef float f32x4 __attribute__((ext_vector_type(4)));
typedef unsigned short ushort4_t __attribute__((ext_vector_type(4)));

__device__ __forceinline__ float gelu_f(float v) {
    return 0.5f * v * (1.0f + erff(v * 0.70710678118654752440f));
}
__device__ __forceinline__ float softplus_f(float z) {
    return fmaxf(z, 0.0f) + log1pf(expf(-fabsf(z)));
}
__device__ __forceinline__ ushort_t f2bf(float f) {
    union { float f; unsigned u; } v; v.f = f;
    unsigned r = v.u + 0x7fffu + ((v.u >> 16) & 1u);
    return (ushort_t)(r >> 16);
}
__device__ __forceinline__ float bf2f(ushort_t h) {
    union { unsigned u; float f; } v; v.u = ((unsigned)h) << 16;
    return v.f;
}
__device__ __forceinline__ float4 f4add(float4 a, float4 b) {
    a.x += b.x; a.y += b.y; a.z += b.z; a.w += b.w; return a;
}
__device__ __forceinline__ ushort4_t pack4(f32x4 v, float4 c) {
    ushort4_t w;
    w.x = f2bf(gelu_f(v[0] + c.x));
    w.y = f2bf(gelu_f(v[1] + c.y));
    w.z = f2bf(gelu_f(v[2] + c.z));
    w.w = f2bf(gelu_f(v[3] + c.w));
    return w;
}
__device__ __forceinline__ ushort4_t pack4f(float4 v, float4 c) {
    ushort4_t w;
    w.x = f2bf(gelu_f(v.x + c.x));
    w.y = f2bf(gelu_f(v.y + c.y));
    w.z = f2bf(gelu_f(v.z + c.z));
    w.w = f2bf(gelu_f(v.w + c.w));
    return w;
}

// ==== stage1: spatial_mean(192) + lag_dist(192) + xhat-DFT(512), 256 thr ====
__global__ void k_stage1(const float* __restrict__ x, float* __restrict__ ws) {
    __shared__ __align__(16) char smem[4096];
    int bx = blockIdx.x, tid = threadIdx.x;
    if (bx < 192) {
        float* lds = (float*)smem;
        int bt = bx;
        int c = tid & 15, ns = tid >> 4;
        const float* xp = x + (long)bt * (N_ * C_);
        float s = 0.f;
        for (int n = ns; n < N_; n += 16) s += xp[n * C_ + c];
        lds[tid] = s;
        __syncthreads();
        for (int st = 128; st >= 16; st >>= 1) {
            if (tid < st) lds[tid] += lds[tid + st];
            __syncthreads();
        }
        if (tid < 16) ws[OFF_SM + bt * 16 + tid] = lds[tid] * (1.0f / 1024.0f);
    } else if (bx < 384) {
        int j = bx - 192;
        int t = j % P_, b = j / P_;
        float4* red = (float4*)smem;
        const float* xp = x + (long)b * P_ * N_ * C_;
        float s1 = 0.f, s2 = 0.f, s4 = 0.f, s6 = 0.f;
        for (int idx = tid; idx < N_ * C_; idx += 256) {
            float xv[9];
            #pragma unroll
            for (int jj = 0; jj < 9; jj++)
                xv[jj] = (t - jj >= 0) ? xp[(long)(t - jj) * (N_ * C_) + idx] : 0.f;
            float xr[7];
            #pragma unroll
            for (int jj = 0; jj < 7; jj++) {
                int s = t - jj;
                float xt = xv[jj];
                xr[jj] = (s <= 0) ? 0.f
                       : (s == 1) ? (xt - xv[jj + 1])
                       : (xt - (xt + xv[jj + 1] + xv[jj + 2]) * (1.0f / 3.0f));
            }
            if (t >= 1) s1 += fabsf(xr[0] - xr[1]);
            if (t >= 2) s2 += fabsf(xr[0] - xr[2]);
            if (t >= 4) s4 += fabsf(xr[0] - xr[4]);
            if (t >= 6) s6 += fabsf(xr[0] - xr[6]);
        }
        red[tid] = make_float4(s1, s2, s4, s6);
        __syncthreads();
        for (int st = 128; st > 0; st >>= 1) {
            if (tid < st) red[tid] = f4add(red[tid], red[tid + st]);
            __syncthreads();
        }
        if (tid == 0) {
            const float inv = 1.0f / (N_ * C_);
            ws[OFF_DL + (b * 4 + 0) * P_ + t] = red[0].x * inv;
            ws[OFF_DL + (b * 4 + 1) * P_ + t] = red[0].y * inv;
            ws[OFF_DL + (b * 4 + 2) * P_ + t] = red[0].z * inv;
            ws[OFF_DL + (b * 4 + 3) * P_ + t] = red[0].w * inv;
        }
    } else {
        int j = bx - 384;
        int ntile = j & 63, b = j >> 6;
        float* ct = (float*)smem;
        float* st = ct + K_ * P_;
        int n = ntile * 16 + (tid >> 4), c = tid & 15;
        for (int i = tid; i < K_ * P_; i += 256) {
            int k = i / P_, t = i % P_;
            int r = (k * t) % P_;
            float ph = 6.283185307179586f * (float)r / (float)P_;
            ct[i] = cosf(ph);
            st[i] = sinf(ph);
        }
        __syncthreads();
        float re[K_], im[K_];
        #pragma unroll
        for (int k = 0; k < K_; k++) { re[k] = 0.f; im[k] = 0.f; }
        for (int t = 0; t < P_; t++) {
            float v = x[((long)(b * P_ + t) * N_ + n) * C_ + c];
            #pragma unroll
            for (int k = 0; k < K_; k++) {
                re[k] += ct[k * P_ + t] * v;
                im[k] -= st[k * P_ + t] * v;
            }
        }
        ushort_t* xcp = (ushort_t*)(ws + OFF_XC);
        #pragma unroll
        for (int k = 0; k < K_; k++) {
            long xb = ((long)(b * K_ + k) * N_ + n) * 32;
            xcp[xb + c] = f2bf(re[k]);
            xcp[xb + 16 + c] = f2bf(im[k]);
        }
    }
}

// ==== stage2: gating+gamma (8 blocks) + time_emb (192 blocks), 128 thr ====
__global__ void k_stage2(const float* __restrict__ pool_param,
                         const float* __restrict__ pe_w1, const float* __restrict__ pe_b1,
                         const float* __restrict__ pe_w2, const float* __restrict__ pe_b2,
                         const float* __restrict__ noise_w, const float* __restrict__ noise_b,
                         const float* __restrict__ in_proj_b, float* __restrict__ ws) {
    __shared__ float sm[256];
    int bx = blockIdx.x, tid = threadIdx.x;
    if (bx < 8) {
        int b = bx;
        float* d = sm; float* ad = sm + 96; float* med = sm + 192; float* mad = sm + 196;
        float* attb = sm + 200; float* gbuf = sm + 224;
        int li = tid / P_, t = tid - li * P_;
        bool active = tid < 4 * P_;
        if (active) d[li * P_ + t] = ws[OFF_DL + (b * 4 + li) * P_ + t];
        __syncthreads();
        if (active) {
            float v = d[li * P_ + t];
            int rank = 0;
            #pragma unroll
            for (int jj = 0; jj < P_; jj++) {
                float dj = d[li * P_ + jj];
                rank += (dj < v || (dj == v && jj < t)) ? 1 : 0;
            }
            if (rank == 11) med[li] = v;
        }
        __syncthreads();
        if (active) ad[li * P_ + t] = fabsf(d[li * P_ + t] - med[li]);
        __syncthreads();
        if (active) {
            float v = ad[li * P_ + t];
            int rank = 0;
            #pragma unroll
            for (int jj = 0; jj < P_; jj++) {
                float dj = ad[li * P_ + jj];
                rank += (dj < v || (dj == v && jj < t)) ? 1 : 0;
            }
            if (rank == 11) mad[li] = v;
        }
        __syncthreads();
        if (active) {
            float z = (d[li * P_ + t] - med[li]) / (mad[li] * 1.4826f + 1e-6f);
            ad[li * P_ + t] = softplus_f(z);
        }
        __syncthreads();
        if (tid == 0) {
            float g[P_];
            #pragma unroll
            for (int tt = 0; tt < P_; tt++)
                g[tt] = 0.25f * (ad[tt] + ad[P_ + tt] + ad[2 * P_ + tt] + ad[3 * P_ + tt]);
            float c = g[0];
            gbuf[0] = g[0];
            for (int tt = 1; tt < P_; tt++) { c = 0.6f * c + 0.4f * g[tt]; gbuf[tt] = c; }
            float mean = 0.f;
            for (int tt = 0; tt < P_; tt++) mean += gbuf[tt];
            mean *= (1.0f / P_);
            float gate[P_];
            #pragma unroll
            for (int tt = 0; tt < P_; tt++) gate[tt] = 1.0f / (1.0f + expf(-1.5f * (gbuf[tt] - mean)));
            float m = -1e30f;
            float pp[P_];
            #pragma unroll
            for (int tt = 0; tt < P_; tt++) { pp[tt] = pool_param[tt]; m = fmaxf(m, pp[tt]); }
            float ssum = 0.f;
            #pragma unroll
            for (int tt = 0; tt < P_; tt++) { pp[tt] = expf(pp[tt] - m); ssum += pp[tt]; }
            float m2 = -1e30f;
            #pragma unroll
            for (int tt = 0; tt < P_; tt++) { pp[tt] = (pp[tt] / ssum) * (1.0f + gate[tt]); m2 = fmaxf(m2, pp[tt]); }
            float s2 = 0.f;
            #pragma unroll
            for (int tt = 0; tt < P_; tt++) { pp[tt] = expf(pp[tt] - m2); s2 += pp[tt]; }
            #pragma unroll
            for (int tt = 0; tt < P_; tt++) {
                float a = pp[tt] / s2;
                ws[OFF_ATT + b * P_ + tt] = a;
                attb[tt] = a;
            }
        }
        __syncthreads();
        if (tid < K_) {
            int k = tid;
            float cre = 0.f, cim = 0.f;
            for (int t2 = 0; t2 < P_; t2++) {
                int r = (k * t2) % P_;
                float ph = 6.283185307179586f * (float)r / (float)P_;
                float a = attb[t2];
                cre += a * cosf(ph);
                cim += a * sinf(ph);
            }
            float w = (k == 0 || k == 12) ? 1.0f : 2.0f;
            ws[OFF_GAM + b * 32 + k] = (w / 24.0f) * cre;
            ws[OFF_GAM + b * 32 + 16 + k] = -(w / 24.0f) * cim;
        }
    } else {
        int bt = bx - 8;
        int t = bt % P_;
        int k = tid >> 6, o = tid & 63;
        float* p1e = sm;
        float period = (k == 0) ? 24.0f : 72.0f;
        float ph = 6.283185307179586f * (float)t / period;
        float sv = sinf(ph), cv = cosf(ph);
        float v = sv * pe_w1[(k * 2 + 0) * 64 + o] + cv * pe_w1[(k * 2 + 1) * 64 + o] + pe_b1[k * 64 + o];
        p1e[tid] = gelu_f(v);
        __syncthreads();
        float acc = pe_b2[k * 64 + o];
        for (int i = 0; i < 64; i++) acc += p1e[k * 64 + i] * pe_w2[(k * 64 + i) * 64 + o];
        ws[OFF_TE + bt * D_ + tid] = acc + in_proj_b[tid];
        float nacc = noise_b[tid];
        for (int c = 0; c < C_; c++) nacc += ws[OFF_SM + bt * C_ + c] * noise_w[c * 128 + tid];
        ws[OFF_TE + bt * D_ + 128 + tid] = nacc + in_proj_b[128 + tid];
    }
}

// ==== stage3: te_reduce(8) + ab_part(104) + prep_d(208) + prep_w2(256), 256 thr ====
__global__ void k_stage3(const float* __restrict__ in_proj_b, const float* __restrict__ in_proj_w,
                         const float* __restrict__ sfe_w1, const float* __restrict__ sfe_w2,
                         const float* __restrict__ sfe_b2, const float* __restrict__ comb_w1,
                         const float* __restrict__ comb_w2,
                         float* __restrict__ ws, float* __restrict__ out) {
    __shared__ __align__(16) char smem[16640];
    int bx = blockIdx.x, tid = threadIdx.x;
    if (bx < 8) {
        int b = bx;
        float* ct = (float*)smem;
        float* st = ct + K_ * P_;
        float* attl = st + K_ * P_;
        for (int i = tid; i < K_ * P_; i += 256) {
            int k = i / P_, t = i % P_;
            int r = (k * t) % P_;
            float ph = 6.283185307179586f * (float)r / (float)P_;
            ct[i] = cosf(ph);
            st[i] = sinf(ph);
        }
        if (tid < P_) attl[tid] = ws[OFF_ATT + b * P_ + tid];
        __syncthreads();
        float fre[K_], fim[K_];
        #pragma unroll
        for (int k = 0; k < K_; k++) { fre[k] = 0.f; fim[k] = 0.f; }
        float smn = 0.f, sa = 0.f;
        for (int t = 0; t < P_; t++) {
            float v = ws[OFF_TE + (b * P_ + t) * D_ + tid];
            smn += v;
            sa += attl[t] * v;
            #pragma unroll
            for (int k = 0; k < K_; k++) {
                fre[k] += ct[k * P_ + t] * v;
                fim[k] -= st[k * P_ + t] * v;
            }
        }
        out[2097152 + b * D_ + tid] = smn * (1.0f / P_) - in_proj_b[tid];
        ws[OFF_ZWC + b * D_ + tid] = sa;
        #pragma unroll
        for (int k = 0; k < K_; k++) {
            ws[OFF_FTR + (b * K_ + k) * D_ + tid] = fre[k];
            ws[OFF_FTI + (b * K_ + k) * D_ + tid] = fim[k];
        }
    } else if (bx < 112) {
        int j = bx - 8;
        int k = j >> 3, et = j & 7;
        int o = tid;
        float accA[C_], accB[C_];
        #pragma unroll
        for (int c = 0; c < C_; c++) { accA[c] = 0.f; accB[c] = 0.f; }
        const float* w1r = sfe_w1 + (long)k * 512 * 256;
        const float* w1i = w1r + 256 * 256;
        for (int e = et * 32; e < et * 32 + 32; e++) {
            float vr = w1r[e * 256 + o];
            float vi = w1i[e * 256 + o];
            #pragma unroll
            for (int c = 0; c < C_; c++) {
                float w = in_proj_w[c * 256 + e];
                accA[c] += w * vr;
                accB[c] += w * vi;
            }
        }
        float* abp = ws + OFF_ABP + (long)((k * 8 + et) * 32) * 256;
        #pragma unroll
        for (int c = 0; c < C_; c++) {
            abp[c * 256 + o] = accA[c];
            abp[(16 + c) * 256 + o] = accB[c];
        }
    } else if (bx < 320) {
        int j = bx - 112;
        int qt0 = (j & 3) * 64, it0 = ((j >> 2) & 3) * 64, k = j >> 4;
        float* As = (float*)smem;        // 64*33
        float* Bs = As + 64 * 33;        // 32*64
        int tq = tid & 15, ti = tid >> 4;
        float acc[4][4];
        #pragma unroll
        for (int r = 0; r < 4; r++)
            #pragma unroll
            for (int c = 0; c < 4; c++) acc[r][c] = 0.f;
        float bias = 0.f;
        for (int step = 0; step < 8; step++) {
            int ob = step * 32;
            __syncthreads();
            #pragma unroll
            for (int u = 0; u < 8; u++) {
                int idx = u * 256 + tid;
                int i = idx >> 5, o = idx & 31;
                As[i * 33 + o] = sfe_w2[((long)(k * 256 + it0 + i) << 8) + ob + o];
            }
            #pragma unroll
            for (int u = 0; u < 8; u++) {
                int idx = u * 256 + tid;
                int o = idx >> 6, q = idx & 63;
                Bs[o * 64 + q] = comb_w1[((long)(k * 256 + ob + o) << 8) + qt0 + q];
            }
            __syncthreads();
            if (it0 == 0 && tid < 64) {
                #pragma unroll
                for (int o = 0; o < 32; o++)
                    bias += sfe_b2[k * 256 + ob + o] * Bs[o * 64 + tid];
            }
            #pragma unroll 4
            for (int o = 0; o < 32; o++) {
                const float4 bv = *(const float4*)&Bs[o * 64 + tq * 4];
                float a[4];
                #pragma unroll
                for (int r = 0; r < 4; r++) a[r] = As[(ti * 4 + r) * 33 + o];
                #pragma unroll
                for (int r = 0; r < 4; r++) {
                    acc[r][0] += a[r] * bv.x;
                    acc[r][1] += a[r] * bv.y;
                    acc[r][2] += a[r] * bv.z;
                    acc[r][3] += a[r] * bv.w;
                }
            }
        }
        ushort_t* dtp = (ushort_t*)(ws + OFF_DD);
        #pragma unroll
        for (int c = 0; c < 4; c++)
            #pragma unroll
            for (int r = 0; r < 4; r++)
                dtp[((k * 256 + qt0 + tq * 4 + c) << 8) + it0 + ti * 4 + r] = f2bf(acc[r][c]);
        if (it0 == 0 && tid < 64)
            ws[OFF_BC + k * 256 + qt0 + tid] = bias;
    } else {
        int q2 = bx - 320;
        ushort_t* w2e = (ushort_t*)(ws + OFF_W2E);
        for (int i = tid; i < 288; i += 256) {
            float v = 0.f;
            if (i < 256) v = comb_w2[(i << 8) + q2];
            else if (i < 272) v = in_proj_w[((i - 256) << 8) + q2] * (1.0f / 0.3f);
            w2e[q2 * 288 + i] = f2bf(v);
        }
    }
}

// ==== stage4: ab_red(13) + c1(104) + xw-from-Xhat(512), 256 thr ====
__global__ void k_stage4(const float* __restrict__ sfe_w1, const float* __restrict__ sfe_b1,
                         float* __restrict__ ws) {
    __shared__ __align__(16) char smem[2608];
    int bx = blockIdx.x, tid = threadIdx.x;
    if (bx < 13) {
        int k = bx, o = tid;
        ushort_t* abt = (ushort_t*)(ws + OFF_AB);
        const float* base = ws + OFF_ABP + (long)(k * 8 * 32) * 256;
        #pragma unroll
        for (int ch = 0; ch < 32; ch++) {
            float s = 0.f;
            #pragma unroll
            for (int et = 0; et < 8; et++) s += base[(et * 32 + ch) * 256 + o];
            abt[(k * 256 + o) * 32 + ch] = f2bf(s);
        }
    } else if (bx < 117) {
        int j = bx - 13;
        int k = j >> 3, ec = j & 7;
        float* F = (float*)smem;  // [8b][64c]
        for (int i = tid; i < 512; i += 256) {
            int bb = i >> 6, cc = i & 63;
            int cg = ec * 64 + cc;
            F[i] = (cg < 256) ? ws[OFF_FTR + (bb * K_ + k) * D_ + cg]
                              : ws[OFF_FTI + (bb * K_ + k) * D_ + cg - 256];
        }
        __syncthreads();
        int o = tid;
        float acc[8];
        float b1 = (ec == 0) ? sfe_b1[k * 256 + o] : 0.f;
        #pragma unroll
        for (int bb = 0; bb < 8; bb++) acc[bb] = b1;
        const float* w1 = sfe_w1 + (long)k * 512 * 256 + (long)(ec * 64) * 256;
        for (int c = 0; c < 64; c++) {
            float w = w1[c * 256 + o];
            #pragma unroll
            for (int bb = 0; bb < 8; bb++) acc[bb] += F[bb * 64 + c] * w;
        }
        #pragma unroll
        for (int bb = 0; bb < 8; bb++)
            ws[OFF_C1P + (long)(((bb * K_ + k) * 8) + ec) * 256 + o] = acc[bb];
    } else {
        int j = bx - 117;
        int ntile = j & 63, b = j >> 6;
        int n = ntile * 16 + (tid >> 4), c = tid & 15;
        float gre[K_], gim[K_];
        #pragma unroll
        for (int k = 0; k < K_; k++) {
            gre[k] = ws[OFF_GAM + b * 32 + k];
            gim[k] = ws[OFF_GAM + b * 32 + 16 + k];
        }
        const ushort_t* xcp = (const ushort_t*)(ws + OFF_XC);
        float acc = 0.f;
        #pragma unroll
        for (int k = 0; k < K_; k++) {
            long xb = ((long)(b * K_ + k) * N_ + n) * 32;
            acc += gre[k] * bf2f(xcp[xb + c]) + gim[k] * bf2f(xcp[xb + 16 + c]);
        }
        ws[OFF_XW + ((long)b * N_ + n) * C_ + c] = acc;
    }
}

// pack-stage for one k: c1 loads + p-MFMA + gelu-pack (no LDS access)
__device__ __forceinline__ void pack_stage(
        const float* __restrict__ ws, const ushort_t* __restrict__ xch,
        const ushort_t* __restrict__ abt, int b, int kk, int n0,
        int l15, int quad, int wq0, int oc0, int oc1, ushort4_t* w) {
    long xb = ((long)(b * K_ + kk) * N_ + n0) * 32;
    bf16x8 pa0 = *(const bf16x8*)&xch[xb + l15 * 32 + quad * 8];
    bf16x8 pa1 = *(const bf16x8*)&xch[xb + (16 + l15) * 32 + quad * 8];
    const ushort_t* ab = abt + (kk * 256 + wq0 + l15) * 32 + quad * 8;
    bf16x8 pb0 = *(const bf16x8*)ab;
    bf16x8 pb1 = *(const bf16x8*)(ab + 16 * 32);
    float4 c10 = make_float4(0.f, 0.f, 0.f, 0.f), c11 = c10;
    #pragma unroll
    for (int ec = 0; ec < 8; ec++) {
        const float* cp = ws + OFF_C1P + (long)(((b * K_ + kk) * 8) + ec) * 256;
        c10 = f4add(c10, *(const float4*)&cp[oc0]);
        c11 = f4add(c11, *(const float4*)&cp[oc1]);
    }
    f32x4 p00 = {}, p01 = {}, p10 = {}, p11 = {};
    p00 = __builtin_amdgcn_mfma_f32_16x16x32_bf16(pb0, pa0, p00, 0, 0, 0);
    p01 = __builtin_amdgcn_mfma_f32_16x16x32_bf16(pb0, pa1, p01, 0, 0, 0);
    p10 = __builtin_amdgcn_mfma_f32_16x16x32_bf16(pb1, pa0, p10, 0, 0, 0);
    p11 = __builtin_amdgcn_mfma_f32_16x16x32_bf16(pb1, pa1, p11, 0, 0, 0);
    w[0] = pack4(p00, c10);
    w[1] = pack4(p01, c10);
    w[2] = pack4(p10, c11);
    w[3] = pack4(p11, c11);
}

// ==== k_final1: split-k(2) GEMM1 partial, 32n tile, SINGLE 16.9KB slab ====
// Occupancy math (R7-R10 evidence): LDS pool ~64KB/CU -> 16.9KB slab allows
// 2-3 blocks; VGPR ~76-90 at cap 128 -> 4 waves/SIMD = 2 blocks/CU. Grid
// 512 blocks = exactly 2/CU across 256 CUs. launch_bounds(512,4) = cap 128:
// (512,6)=cap 85 spilled (VGPR 40 + 200MB scratch WRITE, R6 & R10).
__global__ __launch_bounds__(512, 4) void k_final1(
        const float* __restrict__ ws, const ushort_t* __restrict__ xch,
        const ushort_t* __restrict__ abt, float* __restrict__ pacc) {
    int ntile = blockIdx.x, b = blockIdx.y, kh = blockIdx.z;
    int n0 = ntile * 32;
    const int k0 = kh ? 7 : 0;
    const int k1 = kh ? K_ : 7;
    int tid = threadIdx.x;
    int lane = tid & 63, wave = tid >> 6;
    int l15 = lane & 15, quad = lane >> 4;
    int wq0 = wave * 32;
    __shared__ ushort_t sl[32 * 264];    // 16896 B
    const ushort_t* dt = (const ushort_t*)(ws + OFF_DD);
    int oc0 = wq0 + quad * 4, oc1 = oc0 + 16;
    f32x4 a00 = {}, a01 = {}, a10 = {}, a11 = {};
    ushort4_t w[4];
    pack_stage(ws, xch, abt, b, k0, n0, l15, quad, wq0, oc0, oc1, w);
    for (int k = k0; k < k1; k++) {
        __syncthreads();   // all reads of sl from k-1 complete
        *(ushort4_t*)&sl[l15 * 264 + oc0] = w[0];
        *(ushort4_t*)&sl[(16 + l15) * 264 + oc0] = w[1];
        *(ushort4_t*)&sl[l15 * 264 + oc1] = w[2];
        *(ushort4_t*)&sl[(16 + l15) * 264 + oc1] = w[3];
        __syncthreads();   // writes visible
        if (k + 1 < k1)
            pack_stage(ws, xch, abt, b, k + 1, n0, l15, quad, wq0, oc0, oc1, w);
        // GEMM1 swapped: D[q'][n] = dt x slab^T
        const ushort_t* dbase = dt + (((long)(k * 256 + wq0 + l15)) << 8);
        #pragma unroll
        for (int s = 0; s < 8; s++) {
            int i0 = s * 32 + quad * 8;
            bf16x8 A0 = *(const bf16x8*)(dbase + i0);
            bf16x8 A1 = *(const bf16x8*)(dbase + (16 << 8) + i0);
            bf16x8 B0 = *(const bf16x8*)&sl[l15 * 264 + i0];
            bf16x8 B1 = *(const bf16x8*)&sl[(16 + l15) * 264 + i0];
            a00 = __builtin_amdgcn_mfma_f32_16x16x32_bf16(A0, B0, a00, 0, 0, 0);
            a01 = __builtin_amdgcn_mfma_f32_16x16x32_bf16(A0, B1, a01, 0, 0, 0);
            a10 = __builtin_amdgcn_mfma_f32_16x16x32_bf16(A1, B0, a10, 0, 0, 0);
            a11 = __builtin_amdgcn_mfma_f32_16x16x32_bf16(A1, B1, a11, 0, 0, 0);
        }
    }
    float* pp = pacc + ((long)(kh * 8 + b) * N_ + n0) * 256;
    *(float4*)&pp[(l15 << 8) + oc0] = make_float4(a00[0], a00[1], a00[2], a00[3]);
    *(float4*)&pp[((16 + l15) << 8) + oc0] = make_float4(a01[0], a01[1], a01[2], a01[3]);
    *(float4*)&pp[(l15 << 8) + oc1] = make_float4(a10[0], a10[1], a10[2], a10[3]);
    *(float4*)&pp[((16 + l15) << 8) + oc1] = make_float4(a11[0], a11[1], a11[2], a11[3]);
}

// ==== k_final2: sum 2 partials -> bias+gelu -> GEMM2 -> z, 32n tile ====
__global__ __launch_bounds__(512, 2) void k_final2(
        const float* __restrict__ ws, const float* __restrict__ pacc,
        const float* __restrict__ comb_b1, const float* __restrict__ comb_b2,
        float* __restrict__ out) {
    int ntile = blockIdx.x, b = blockIdx.y;  // 32 x 8
    int n0 = ntile * 32;
    int tid = threadIdx.x;
    int lane = tid & 63, wave = tid >> 6;
    int l15 = lane & 15, quad = lane >> 4;
    int wq0 = wave * 32;
    __shared__ ushort_t sh2[32 * 296];
    const ushort_t* w2e = (const ushort_t*)(ws + OFF_W2E);
    int oc0 = wq0 + quad * 4, oc1 = oc0 + 16;
    const float* p0 = pacc + ((long)(0 * 8 + b) * N_ + n0) * 256;
    const float* p1 = pacc + ((long)(1 * 8 + b) * N_ + n0) * 256;
    float4 s00 = f4add(*(const float4*)&p0[(l15 << 8) + oc0], *(const float4*)&p1[(l15 << 8) + oc0]);
    float4 s01 = f4add(*(const float4*)&p0[((16 + l15) << 8) + oc0], *(const float4*)&p1[((16 + l15) << 8) + oc0]);
    float4 s10 = f4add(*(const float4*)&p0[(l15 << 8) + oc1], *(const float4*)&p1[(l15 << 8) + oc1]);
    float4 s11 = f4add(*(const float4*)&p0[((16 + l15) << 8) + oc1], *(const float4*)&p1[((16 + l15) << 8) + oc1]);
    float4 bc0 = *(const float4*)&comb_b1[oc0];
    float4 bc1 = *(const float4*)&comb_b1[oc1];
    #pragma unroll
    for (int k = 0; k < K_; k++) {
        bc0 = f4add(bc0, *(const float4*)&ws[OFF_BC + k * 256 + oc0]);
        bc1 = f4add(bc1, *(const float4*)&ws[OFF_BC + k * 256 + oc1]);
    }
    *(ushort4_t*)&sh2[l15 * 296 + oc0]        = pack4f(s00, bc0);
    *(ushort4_t*)&sh2[(16 + l15) * 296 + oc0] = pack4f(s01, bc0);
    *(ushort4_t*)&sh2[l15 * 296 + oc1]        = pack4f(s10, bc1);
    *(ushort4_t*)&sh2[(16 + l15) * 296 + oc1] = pack4f(s11, bc1);
    {
        int row = tid >> 4, cc = tid & 15;  // 32 rows x 16 c
        float xv = ws[OFF_XW + ((long)b * N_ + n0 + row) * C_ + cc];
        sh2[row * 296 + 256 + cc] = f2bf(xv);
        sh2[row * 296 + 272 + cc] = 0;
    }
    __syncthreads();
    // GEMM2 swapped: D[q2][n] = w2e x Uext^T
    f32x4 h00 = {}, h01 = {}, h10 = {}, h11 = {};
    #pragma unroll
    for (int s = 0; s < 9; s++) {
        int i0 = s * 32 + quad * 8;
        bf16x8 A0 = *(const bf16x8*)&w2e[(wq0 + l15) * 288 + i0];
        bf16x8 A1 = *(const bf16x8*)&w2e[(wq0 + 16 + l15) * 288 + i0];
        bf16x8 B0 = *(const bf16x8*)&sh2[l15 * 296 + i0];
        bf16x8 B1 = *(const bf16x8*)&sh2[(16 + l15) * 296 + i0];
        h00 = __builtin_amdgcn_mfma_f32_16x16x32_bf16(A0, B0, h00, 0, 0, 0);
        h01 = __builtin_amdgcn_mfma_f32_16x16x32_bf16(A0, B1, h01, 0, 0, 0);
        h10 = __builtin_amdgcn_mfma_f32_16x16x32_bf16(A1, B0, h10, 0, 0, 0);
        h11 = __builtin_amdgcn_mfma_f32_16x16x32_bf16(A1, B1, h11, 0, 0, 0);
    }
    float4 zc0 = *(const float4*)&ws[OFF_ZWC + b * 256 + oc0];
    float4 zc1 = *(const float4*)&ws[OFF_ZWC + b * 256 + oc1];
    float4 cb0 = *(const float4*)&comb_b2[oc0];
    float4 cb1 = *(const float4*)&comb_b2[oc1];
    long ob = ((long)b * N_ + n0) << 8;
    float4 o00, o01, o10, o11;
    o00.x = zc0.x + 0.3f * (h00[0] + cb0.x); o00.y = zc0.y + 0.3f * (h00[1] + cb0.y);
    o00.z = zc0.z + 0.3f * (h00[2] + cb0.z); o00.w = zc0.w + 0.3f * (h00[3] + cb0.w);
    o01.x = zc0.x + 0.3f * (h01[0] + cb0.x); o01.y = zc0.y + 0.3f * (h01[1] + cb0.y);
    o01.z = zc0.z + 0.3f * (h01[2] + cb0.z); o01.w = zc0.w + 0.3f * (h01[3] + cb0.w);
    o10.x = zc1.x + 0.3f * (h10[0] + cb1.x); o10.y = zc1.y + 0.3f * (h10[1] + cb1.y);
    o10.z = zc1.z + 0.3f * (h10[2] + cb1.z); o10.w = zc1.w + 0.3f * (h10[3] + cb1.w);
    o11.x = zc1.x + 0.3f * (h11[0] + cb1.x); o11.y = zc1.y + 0.3f * (h11[1] + cb1.y);
    o11.z = zc1.z + 0.3f * (h11[2] + cb1.z); o11.w = zc1.w + 0.3f * (h11[3] + cb1.w);
    *(float4*)&out[ob + ((long)l15 << 8) + oc0] = o00;
    *(float4*)&out[ob + ((long)(16 + l15) << 8) + oc0] = o01;
    *(float4*)&out[ob + ((long)l15 << 8) + oc1] = o10;
    *(float4*)&out[ob + ((long)(16 + l15) << 8) + oc1] = o11;
}

extern "C" void kernel_launch(void* const* d_in, const int* in_sizes, int n_in,
                              void* d_out, int out_size, void* d_ws, size_t ws_size,
                              hipStream_t stream) {
    const float* x = (const float*)d_in[0];
    const float* in_proj_w = (const float*)d_in[1];
    const float* in_proj_b = (const float*)d_in[2];
    const float* pe_w1 = (const float*)d_in[3];
    const float* pe_b1 = (const float*)d_in[4];
    const float* pe_w2 = (const float*)d_in[5];
    const float* pe_b2 = (const float*)d_in[6];
    const float* noise_w = (const float*)d_in[7];
    const float* noise_b = (const float*)d_in[8];
    const float* sfe_w1 = (const float*)d_in[9];
    const float* sfe_b1 = (const float*)d_in[10];
    const float* sfe_w2 = (const float*)d_in[11];
    const float* sfe_b2 = (const float*)d_in[12];
    const float* comb_w1 = (const float*)d_in[13];
    const float* comb_b1 = (const float*)d_in[14];
    const float* comb_w2 = (const float*)d_in[15];
    const float* comb_b2 = (const float*)d_in[16];
    const float* pool_param = (const float*)d_in[17];
    float* ws = (float*)d_ws;
    float* out = (float*)d_out;

    hipLaunchKernelGGL(k_stage1, dim3(896), dim3(256), 0, stream, x, ws);
    hipLaunchKernelGGL(k_stage2, dim3(200), dim3(128), 0, stream,
                       pool_param, pe_w1, pe_b1, pe_w2, pe_b2, noise_w, noise_b, in_proj_b, ws);
    hipLaunchKernelGGL(k_stage3, dim3(576), dim3(256), 0, stream,
                       in_proj_b, in_proj_w, sfe_w1, sfe_w2, sfe_b2, comb_w1, comb_w2, ws, out);
    hipLaunchKernelGGL(k_stage4, dim3(629), dim3(256), 0, stream, sfe_w1, sfe_b1, ws);
    hipLaunchKernelGGL(k_final1, dim3(32, 8, 2), dim3(512), 0, stream,
                       ws, (const ushort_t*)(ws + OFF_XC), (const ushort_t*)(ws + OFF_AB),
                       ws + OFF_PACC);
    hipLaunchKernelGGL(k_final2, dim3(32, 8), dim3(512), 0, stream,
                       ws, ws + OFF_PACC, comb_b1, comb_b2, out);
}

// Round 12
// 239.620 us; speedup vs baseline: 1.4778x; 1.1433x over previous
//
#include <hip/hip_runtime.h>
#include <hip/hip_bf16.h>
#include <math.h>

#define B_ 8
#define P_ 24
#define N_ 1024
#define C_ 16
#define D_ 256
#define K_ 13

// workspace offsets (in floats)
#define OFF_SM   0          // spatial_mean: 192*16
#define OFF_DL   4096       // d_lag: 8*4*24
#define OFF_ATT  8192       // att: 8*24
#define OFF_GAM  9216       // gamma: 8*32 (re[13] @ +0, im[13] @ +16)
#define OFF_TE   12288      // te_fold: 192*256
#define OFF_FTR  65536      // Fte_re: 8*13*256
#define OFF_FTI  94208      // Fte_im
#define OFF_ZWC  122880     // zw_const: 8*256
#define OFF_AB   126976     // ABt bf16 FRAGMENT order [k][wave][half][lane][8]
#define OFF_BC   266240     // bias_comb: 13*256
#define OFF_DD   270336     // Dt bf16 FRAGMENT order [k][wave][s][half][lane][8]
#define OFF_W2E  696320     // W2ext bf16 [q2][288]
#define OFF_XC   1126400    // Xhat bf16 FRAGMENT order [b][k][nt32][half][lane][8]
#define OFF_XW   2830336    // xw fp32: 8*1024*16
#define OFF_ABP  3000000    // AB partials fp32 [k][et][32ch][256o]
#define OFF_C1P  3900000    // c1 partials fp32 [b][k][8ec][256]
#define OFF_PACC 4194304    // GEMM1 split-k partials fp32, fragment order

typedef unsigned short ushort_t;
typedef __bf16 bf16x8 __attribute__((ext_vector_type(8)));
typedef float f32x4 __attribute__((ext_vector_type(4)));
typedef unsigned short ushort4_t __attribute__((ext_vector_type(4)));

__device__ __forceinline__ float gelu_f(float v) {
    return 0.5f * v * (1.0f + erff(v * 0.70710678118654752440f));
}
__device__ __forceinline__ float softplus_f(float z) {
    return fmaxf(z, 0.0f) + log1pf(expf(-fabsf(z)));
}
__device__ __forceinline__ ushort_t f2bf(float f) {
    union { float f; unsigned u; } v; v.f = f;
    unsigned r = v.u + 0x7fffu + ((v.u >> 16) & 1u);
    return (ushort_t)(r >> 16);
}
__device__ __forceinline__ float bf2f(ushort_t h) {
    union { unsigned u; float f; } v; v.u = ((unsigned)h) << 16;
    return v.f;
}
__device__ __forceinline__ float4 f4add(float4 a, float4 b) {
    a.x += b.x; a.y += b.y; a.z += b.z; a.w += b.w; return a;
}
__device__ __forceinline__ ushort4_t pack4(f32x4 v, float4 c) {
    ushort4_t w;
    w.x = f2bf(gelu_f(v[0] + c.x));
    w.y = f2bf(gelu_f(v[1] + c.y));
    w.z = f2bf(gelu_f(v[2] + c.z));
    w.w = f2bf(gelu_f(v[3] + c.w));
    return w;
}
__device__ __forceinline__ ushort4_t pack4f(float4 v, float4 c) {
    ushort4_t w;
    w.x = f2bf(gelu_f(v.x + c.x));
    w.y = f2bf(gelu_f(v.y + c.y));
    w.z = f2bf(gelu_f(v.z + c.z));
    w.w = f2bf(gelu_f(v.w + c.w));
    return w;
}

// ==== stage1: spatial_mean(192) + lag_dist(192) + xhat-DFT(512), 256 thr ====
__global__ void k_stage1(const float* __restrict__ x, float* __restrict__ ws) {
    __shared__ __align__(16) char smem[4096];
    int bx = blockIdx.x, tid = threadIdx.x;
    if (bx < 192) {
        float* lds = (float*)smem;
        int bt = bx;
        int c = tid & 15, ns = tid >> 4;
        const float* xp = x + (long)bt * (N_ * C_);
        float s = 0.f;
        for (int n = ns; n < N_; n += 16) s += xp[n * C_ + c];
        lds[tid] = s;
        __syncthreads();
        for (int st = 128; st >= 16; st >>= 1) {
            if (tid < st) lds[tid] += lds[tid + st];
            __syncthreads();
        }
        if (tid < 16) ws[OFF_SM + bt * 16 + tid] = lds[tid] * (1.0f / 1024.0f);
    } else if (bx < 384) {
        int j = bx - 192;
        int t = j % P_, b = j / P_;
        float4* red = (float4*)smem;
        const float* xp = x + (long)b * P_ * N_ * C_;
        float s1 = 0.f, s2 = 0.f, s4 = 0.f, s6 = 0.f;
        for (int idx = tid; idx < N_ * C_; idx += 256) {
            float xv[9];
            #pragma unroll
            for (int jj = 0; jj < 9; jj++)
                xv[jj] = (t - jj >= 0) ? xp[(long)(t - jj) * (N_ * C_) + idx] : 0.f;
            float xr[7];
            #pragma unroll
            for (int jj = 0; jj < 7; jj++) {
                int s = t - jj;
                float xt = xv[jj];
                xr[jj] = (s <= 0) ? 0.f
                       : (s == 1) ? (xt - xv[jj + 1])
                       : (xt - (xt + xv[jj + 1] + xv[jj + 2]) * (1.0f / 3.0f));
            }
            if (t >= 1) s1 += fabsf(xr[0] - xr[1]);
            if (t >= 2) s2 += fabsf(xr[0] - xr[2]);
            if (t >= 4) s4 += fabsf(xr[0] - xr[4]);
            if (t >= 6) s6 += fabsf(xr[0] - xr[6]);
        }
        red[tid] = make_float4(s1, s2, s4, s6);
        __syncthreads();
        for (int st = 128; st > 0; st >>= 1) {
            if (tid < st) red[tid] = f4add(red[tid], red[tid + st]);
            __syncthreads();
        }
        if (tid == 0) {
            const float inv = 1.0f / (N_ * C_);
            ws[OFF_DL + (b * 4 + 0) * P_ + t] = red[0].x * inv;
            ws[OFF_DL + (b * 4 + 1) * P_ + t] = red[0].y * inv;
            ws[OFF_DL + (b * 4 + 2) * P_ + t] = red[0].z * inv;
            ws[OFF_DL + (b * 4 + 3) * P_ + t] = red[0].w * inv;
        }
    } else {
        // xhat DFT -> FRAGMENT-ordered xc2
        int j = bx - 384;
        int ntile = j & 63, b = j >> 6;
        float* ct = (float*)smem;
        float* st = ct + K_ * P_;
        int n = ntile * 16 + (tid >> 4), c = tid & 15;
        for (int i = tid; i < K_ * P_; i += 256) {
            int k = i / P_, t = i % P_;
            int r = (k * t) % P_;
            float ph = 6.283185307179586f * (float)r / (float)P_;
            ct[i] = cosf(ph);
            st[i] = sinf(ph);
        }
        __syncthreads();
        float re[K_], im[K_];
        #pragma unroll
        for (int k = 0; k < K_; k++) { re[k] = 0.f; im[k] = 0.f; }
        for (int t = 0; t < P_; t++) {
            float v = x[((long)(b * P_ + t) * N_ + n) * C_ + c];
            #pragma unroll
            for (int k = 0; k < K_; k++) {
                re[k] += ct[k * P_ + t] * v;
                im[k] -= st[k * P_ + t] * v;
            }
        }
        ushort_t* xcp = (ushort_t*)(ws + OFF_XC);
        int nt32 = n >> 5, halfn = (n >> 4) & 1, l15n = n & 15;
        int lre = ((c >> 3) * 16 + l15n) * 8 + (c & 7);
        int lim = ((2 + (c >> 3)) * 16 + l15n) * 8 + (c & 7);
        #pragma unroll
        for (int k = 0; k < K_; k++) {
            long base = ((((long)(b * K_ + k) * 32 + nt32) * 2 + halfn) * 64) * 8;
            xcp[base + lre] = f2bf(re[k]);
            xcp[base + lim] = f2bf(im[k]);
        }
    }
}

// ==== stage2: gating+gamma (8 blocks) + time_emb (192 blocks), 128 thr ====
__global__ void k_stage2(const float* __restrict__ pool_param,
                         const float* __restrict__ pe_w1, const float* __restrict__ pe_b1,
                         const float* __restrict__ pe_w2, const float* __restrict__ pe_b2,
                         const float* __restrict__ noise_w, const float* __restrict__ noise_b,
                         const float* __restrict__ in_proj_b, float* __restrict__ ws) {
    __shared__ float sm[256];
    int bx = blockIdx.x, tid = threadIdx.x;
    if (bx < 8) {
        int b = bx;
        float* d = sm; float* ad = sm + 96; float* med = sm + 192; float* mad = sm + 196;
        float* attb = sm + 200; float* gbuf = sm + 224;
        int li = tid / P_, t = tid - li * P_;
        bool active = tid < 4 * P_;
        if (active) d[li * P_ + t] = ws[OFF_DL + (b * 4 + li) * P_ + t];
        __syncthreads();
        if (active) {
            float v = d[li * P_ + t];
            int rank = 0;
            #pragma unroll
            for (int jj = 0; jj < P_; jj++) {
                float dj = d[li * P_ + jj];
                rank += (dj < v || (dj == v && jj < t)) ? 1 : 0;
            }
            if (rank == 11) med[li] = v;
        }
        __syncthreads();
        if (active) ad[li * P_ + t] = fabsf(d[li * P_ + t] - med[li]);
        __syncthreads();
        if (active) {
            float v = ad[li * P_ + t];
            int rank = 0;
            #pragma unroll
            for (int jj = 0; jj < P_; jj++) {
                float dj = ad[li * P_ + jj];
                rank += (dj < v || (dj == v && jj < t)) ? 1 : 0;
            }
            if (rank == 11) mad[li] = v;
        }
        __syncthreads();
        if (active) {
            float z = (d[li * P_ + t] - med[li]) / (mad[li] * 1.4826f + 1e-6f);
            ad[li * P_ + t] = softplus_f(z);
        }
        __syncthreads();
        if (tid == 0) {
            float g[P_];
            #pragma unroll
            for (int tt = 0; tt < P_; tt++)
                g[tt] = 0.25f * (ad[tt] + ad[P_ + tt] + ad[2 * P_ + tt] + ad[3 * P_ + tt]);
            float c = g[0];
            gbuf[0] = g[0];
            for (int tt = 1; tt < P_; tt++) { c = 0.6f * c + 0.4f * g[tt]; gbuf[tt] = c; }
            float mean = 0.f;
            for (int tt = 0; tt < P_; tt++) mean += gbuf[tt];
            mean *= (1.0f / P_);
            float gate[P_];
            #pragma unroll
            for (int tt = 0; tt < P_; tt++) gate[tt] = 1.0f / (1.0f + expf(-1.5f * (gbuf[tt] - mean)));
            float m = -1e30f;
            float pp[P_];
            #pragma unroll
            for (int tt = 0; tt < P_; tt++) { pp[tt] = pool_param[tt]; m = fmaxf(m, pp[tt]); }
            float ssum = 0.f;
            #pragma unroll
            for (int tt = 0; tt < P_; tt++) { pp[tt] = expf(pp[tt] - m); ssum += pp[tt]; }
            float m2 = -1e30f;
            #pragma unroll
            for (int tt = 0; tt < P_; tt++) { pp[tt] = (pp[tt] / ssum) * (1.0f + gate[tt]); m2 = fmaxf(m2, pp[tt]); }
            float s2 = 0.f;
            #pragma unroll
            for (int tt = 0; tt < P_; tt++) { pp[tt] = expf(pp[tt] - m2); s2 += pp[tt]; }
            #pragma unroll
            for (int tt = 0; tt < P_; tt++) {
                float a = pp[tt] / s2;
                ws[OFF_ATT + b * P_ + tt] = a;
                attb[tt] = a;
            }
        }
        __syncthreads();
        if (tid < K_) {
            int k = tid;
            float cre = 0.f, cim = 0.f;
            for (int t2 = 0; t2 < P_; t2++) {
                int r = (k * t2) % P_;
                float ph = 6.283185307179586f * (float)r / (float)P_;
                float a = attb[t2];
                cre += a * cosf(ph);
                cim += a * sinf(ph);
            }
            float w = (k == 0 || k == 12) ? 1.0f : 2.0f;
            ws[OFF_GAM + b * 32 + k] = (w / 24.0f) * cre;
            ws[OFF_GAM + b * 32 + 16 + k] = -(w / 24.0f) * cim;
        }
    } else {
        int bt = bx - 8;
        int t = bt % P_;
        int k = tid >> 6, o = tid & 63;
        float* p1e = sm;
        float period = (k == 0) ? 24.0f : 72.0f;
        float ph = 6.283185307179586f * (float)t / period;
        float sv = sinf(ph), cv = cosf(ph);
        float v = sv * pe_w1[(k * 2 + 0) * 64 + o] + cv * pe_w1[(k * 2 + 1) * 64 + o] + pe_b1[k * 64 + o];
        p1e[tid] = gelu_f(v);
        __syncthreads();
        float acc = pe_b2[k * 64 + o];
        for (int i = 0; i < 64; i++) acc += p1e[k * 64 + i] * pe_w2[(k * 64 + i) * 64 + o];
        ws[OFF_TE + bt * D_ + tid] = acc + in_proj_b[tid];
        float nacc = noise_b[tid];
        for (int c = 0; c < C_; c++) nacc += ws[OFF_SM + bt * C_ + c] * noise_w[c * 128 + tid];
        ws[OFF_TE + bt * D_ + 128 + tid] = nacc + in_proj_b[128 + tid];
    }
}

// ==== stage3: te_reduce(8) + ab_part(104) + prep_d(208) + prep_w2(256), 256 thr ====
__global__ void k_stage3(const float* __restrict__ in_proj_b, const float* __restrict__ in_proj_w,
                         const float* __restrict__ sfe_w1, const float* __restrict__ sfe_w2,
                         const float* __restrict__ sfe_b2, const float* __restrict__ comb_w1,
                         const float* __restrict__ comb_w2,
                         float* __restrict__ ws, float* __restrict__ out) {
    __shared__ __align__(16) char smem[16640];
    int bx = blockIdx.x, tid = threadIdx.x;
    if (bx < 8) {
        int b = bx;
        float* ct = (float*)smem;
        float* st = ct + K_ * P_;
        float* attl = st + K_ * P_;
        for (int i = tid; i < K_ * P_; i += 256) {
            int k = i / P_, t = i % P_;
            int r = (k * t) % P_;
            float ph = 6.283185307179586f * (float)r / (float)P_;
            ct[i] = cosf(ph);
            st[i] = sinf(ph);
        }
        if (tid < P_) attl[tid] = ws[OFF_ATT + b * P_ + tid];
        __syncthreads();
        float fre[K_], fim[K_];
        #pragma unroll
        for (int k = 0; k < K_; k++) { fre[k] = 0.f; fim[k] = 0.f; }
        float smn = 0.f, sa = 0.f;
        for (int t = 0; t < P_; t++) {
            float v = ws[OFF_TE + (b * P_ + t) * D_ + tid];
            smn += v;
            sa += attl[t] * v;
            #pragma unroll
            for (int k = 0; k < K_; k++) {
                fre[k] += ct[k * P_ + t] * v;
                fim[k] -= st[k * P_ + t] * v;
            }
        }
        out[2097152 + b * D_ + tid] = smn * (1.0f / P_) - in_proj_b[tid];
        ws[OFF_ZWC + b * D_ + tid] = sa;
        #pragma unroll
        for (int k = 0; k < K_; k++) {
            ws[OFF_FTR + (b * K_ + k) * D_ + tid] = fre[k];
            ws[OFF_FTI + (b * K_ + k) * D_ + tid] = fim[k];
        }
    } else if (bx < 112) {
        int j = bx - 8;
        int k = j >> 3, et = j & 7;
        int o = tid;
        float accA[C_], accB[C_];
        #pragma unroll
        for (int c = 0; c < C_; c++) { accA[c] = 0.f; accB[c] = 0.f; }
        const float* w1r = sfe_w1 + (long)k * 512 * 256;
        const float* w1i = w1r + 256 * 256;
        for (int e = et * 32; e < et * 32 + 32; e++) {
            float vr = w1r[e * 256 + o];
            float vi = w1i[e * 256 + o];
            #pragma unroll
            for (int c = 0; c < C_; c++) {
                float w = in_proj_w[c * 256 + e];
                accA[c] += w * vr;
                accB[c] += w * vi;
            }
        }
        float* abp = ws + OFF_ABP + (long)((k * 8 + et) * 32) * 256;
        #pragma unroll
        for (int c = 0; c < C_; c++) {
            abp[c * 256 + o] = accA[c];
            abp[(16 + c) * 256 + o] = accB[c];
        }
    } else if (bx < 320) {
        int j = bx - 112;
        int qt0 = (j & 3) * 64, it0 = ((j >> 2) & 3) * 64, k = j >> 4;
        float* As = (float*)smem;        // 64*33
        float* Bs = As + 64 * 33;        // 32*64
        int tq = tid & 15, ti = tid >> 4;
        float acc[4][4];
        #pragma unroll
        for (int r = 0; r < 4; r++)
            #pragma unroll
            for (int c = 0; c < 4; c++) acc[r][c] = 0.f;
        float bias = 0.f;
        for (int step = 0; step < 8; step++) {
            int ob = step * 32;
            __syncthreads();
            #pragma unroll
            for (int u = 0; u < 8; u++) {
                int idx = u * 256 + tid;
                int i = idx >> 5, o = idx & 31;
                As[i * 33 + o] = sfe_w2[((long)(k * 256 + it0 + i) << 8) + ob + o];
            }
            #pragma unroll
            for (int u = 0; u < 8; u++) {
                int idx = u * 256 + tid;
                int o = idx >> 6, q = idx & 63;
                Bs[o * 64 + q] = comb_w1[((long)(k * 256 + ob + o) << 8) + qt0 + q];
            }
            __syncthreads();
            if (it0 == 0 && tid < 64) {
                #pragma unroll
                for (int o = 0; o < 32; o++)
                    bias += sfe_b2[k * 256 + ob + o] * Bs[o * 64 + tid];
            }
            #pragma unroll 4
            for (int o = 0; o < 32; o++) {
                const float4 bv = *(const float4*)&Bs[o * 64 + tq * 4];
                float a[4];
                #pragma unroll
                for (int r = 0; r < 4; r++) a[r] = As[(ti * 4 + r) * 33 + o];
                #pragma unroll
                for (int r = 0; r < 4; r++) {
                    acc[r][0] += a[r] * bv.x;
                    acc[r][1] += a[r] * bv.y;
                    acc[r][2] += a[r] * bv.z;
                    acc[r][3] += a[r] * bv.w;
                }
            }
        }
        // write Dt in FRAGMENT order [k][wave][s][half][lane][8]
        ushort_t* dtp = (ushort_t*)(ws + OFF_DD);
        #pragma unroll
        for (int c = 0; c < 4; c++)
            #pragma unroll
            for (int r = 0; r < 4; r++) {
                int q = qt0 + tq * 4 + c, i = it0 + ti * 4 + r;
                int wv = q >> 5, hf = (q >> 4) & 1, l = q & 15;
                int s = i >> 5, qd = (i >> 3) & 3, jj = i & 7;
                long idx = ((((long)(k * 8 + wv) * 8 + s) * 2 + hf) * 64 + qd * 16 + l) * 8 + jj;
                dtp[idx] = f2bf(acc[r][c]);
            }
        if (it0 == 0 && tid < 64)
            ws[OFF_BC + k * 256 + qt0 + tid] = bias;
    } else {
        int q2 = bx - 320;
        ushort_t* w2e = (ushort_t*)(ws + OFF_W2E);
        for (int i = tid; i < 288; i += 256) {
            float v = 0.f;
            if (i < 256) v = comb_w2[(i << 8) + q2];
            else if (i < 272) v = in_proj_w[((i - 256) << 8) + q2] * (1.0f / 0.3f);
            w2e[q2 * 288 + i] = f2bf(v);
        }
    }
}

// ==== stage4: ab_red(13) + c1(104) + xw-from-xc2(512), 256 thr ====
__global__ void k_stage4(const float* __restrict__ sfe_w1, const float* __restrict__ sfe_b1,
                         float* __restrict__ ws) {
    __shared__ __align__(16) char smem[2608];
    int bx = blockIdx.x, tid = threadIdx.x;
    if (bx < 13) {
        // reduce AB partials -> ABt FRAGMENT order [k][wave][half][lane][8]
        int k = bx, o = tid;
        ushort_t* abt = (ushort_t*)(ws + OFF_AB);
        const float* base = ws + OFF_ABP + (long)(k * 8 * 32) * 256;
        int wv = o >> 5, hf = (o >> 4) & 1, l = o & 15;
        long obase = (((long)(k * 8 + wv) * 2 + hf) * 64) * 8;
        #pragma unroll
        for (int ch = 0; ch < 32; ch++) {
            float s = 0.f;
            #pragma unroll
            for (int et = 0; et < 8; et++) s += base[(et * 32 + ch) * 256 + o];
            abt[obase + ((ch >> 3) * 16 + l) * 8 + (ch & 7)] = f2bf(s);
        }
    } else if (bx < 117) {
        int j = bx - 13;
        int k = j >> 3, ec = j & 7;
        float* F = (float*)smem;  // [8b][64c]
        for (int i = tid; i < 512; i += 256) {
            int bb = i >> 6, cc = i & 63;
            int cg = ec * 64 + cc;
            F[i] = (cg < 256) ? ws[OFF_FTR + (bb * K_ + k) * D_ + cg]
                              : ws[OFF_FTI + (bb * K_ + k) * D_ + cg - 256];
        }
        __syncthreads();
        int o = tid;
        float acc[8];
        float b1 = (ec == 0) ? sfe_b1[k * 256 + o] : 0.f;
        #pragma unroll
        for (int bb = 0; bb < 8; bb++) acc[bb] = b1;
        const float* w1 = sfe_w1 + (long)k * 512 * 256 + (long)(ec * 64) * 256;
        for (int c = 0; c < 64; c++) {
            float w = w1[c * 256 + o];
            #pragma unroll
            for (int bb = 0; bb < 8; bb++) acc[bb] += F[bb * 64 + c] * w;
        }
        #pragma unroll
        for (int bb = 0; bb < 8; bb++)
            ws[OFF_C1P + (long)(((bb * K_ + k) * 8) + ec) * 256 + o] = acc[bb];
    } else {
        // xw from fragment-ordered xc2
        int j = bx - 117;
        int ntile = j & 63, b = j >> 6;
        int n = ntile * 16 + (tid >> 4), c = tid & 15;
        float gre[K_], gim[K_];
        #pragma unroll
        for (int k = 0; k < K_; k++) {
            gre[k] = ws[OFF_GAM + b * 32 + k];
            gim[k] = ws[OFF_GAM + b * 32 + 16 + k];
        }
        const ushort_t* xcp = (const ushort_t*)(ws + OFF_XC);
        int nt32 = n >> 5, halfn = (n >> 4) & 1, l15n = n & 15;
        int lre = ((c >> 3) * 16 + l15n) * 8 + (c & 7);
        int lim = ((2 + (c >> 3)) * 16 + l15n) * 8 + (c & 7);
        float acc = 0.f;
        #pragma unroll
        for (int k = 0; k < K_; k++) {
            long base = ((((long)(b * K_ + k) * 32 + nt32) * 2 + halfn) * 64) * 8;
            acc += gre[k] * bf2f(xcp[base + lre]) + gim[k] * bf2f(xcp[base + lim]);
        }
        ws[OFF_XW + ((long)b * N_ + n) * C_ + c] = acc;
    }
}

// pack-stage for one k: coalesced fragment loads + p-MFMA + gelu-pack
__device__ __forceinline__ void pack_stage(
        const float* __restrict__ ws, const ushort_t* __restrict__ xch,
        const ushort_t* __restrict__ abt, int b, int kk, int ntile,
        int wave, int lane, int oc0, int oc1, ushort4_t* w) {
    const ushort_t* xb = xch + (((long)(b * K_ + kk) * 32 + ntile) * 2) * 512 + lane * 8;
    bf16x8 pa0 = *(const bf16x8*)xb;
    bf16x8 pa1 = *(const bf16x8*)(xb + 512);
    const ushort_t* ab = abt + ((long)(kk * 8 + wave) * 2) * 512 + lane * 8;
    bf16x8 pb0 = *(const bf16x8*)ab;
    bf16x8 pb1 = *(const bf16x8*)(ab + 512);
    float4 c10 = make_float4(0.f, 0.f, 0.f, 0.f), c11 = c10;
    #pragma unroll
    for (int ec = 0; ec < 8; ec++) {
        const float* cp = ws + OFF_C1P + (long)(((b * K_ + kk) * 8) + ec) * 256;
        c10 = f4add(c10, *(const float4*)&cp[oc0]);
        c11 = f4add(c11, *(const float4*)&cp[oc1]);
    }
    f32x4 p00 = {}, p01 = {}, p10 = {}, p11 = {};
    p00 = __builtin_amdgcn_mfma_f32_16x16x32_bf16(pb0, pa0, p00, 0, 0, 0);
    p01 = __builtin_amdgcn_mfma_f32_16x16x32_bf16(pb0, pa1, p01, 0, 0, 0);
    p10 = __builtin_amdgcn_mfma_f32_16x16x32_bf16(pb1, pa0, p10, 0, 0, 0);
    p11 = __builtin_amdgcn_mfma_f32_16x16x32_bf16(pb1, pa1, p11, 0, 0, 0);
    w[0] = pack4(p00, c10);
    w[1] = pack4(p01, c10);
    w[2] = pack4(p10, c11);
    w[3] = pack4(p11, c11);
}

// ==== k_final1: split-k(2) GEMM1 partial, 32n tile, coalesced fragment loads ====
// All global operands (dt/xc/ab/pacc) in MFMA-fragment order: lane i reads
// base+i*16B (1 segment) instead of the prior 16-segment row gathers that
// saturated the per-CU address path (R11 evidence: 2 blocks/CU gave no
// speedup -> shared-resource bound, MfmaUtil 8%).
__global__ __launch_bounds__(512, 4) void k_final1(
        const float* __restrict__ ws, const ushort_t* __restrict__ xch,
        const ushort_t* __restrict__ abt, float* __restrict__ pacc) {
    int ntile = blockIdx.x, b = blockIdx.y, kh = blockIdx.z;
    const int k0 = kh ? 7 : 0;
    const int k1 = kh ? K_ : 7;
    int tid = threadIdx.x;
    int lane = tid & 63, wave = tid >> 6;
    int l15 = lane & 15, quad = lane >> 4;
    int wq0 = wave * 32;
    __shared__ ushort_t sl[32 * 264];    // 16896 B
    const ushort_t* dt = (const ushort_t*)(ws + OFF_DD);
    int oc0 = wq0 + quad * 4, oc1 = oc0 + 16;
    f32x4 a00 = {}, a01 = {}, a10 = {}, a11 = {};
    ushort4_t w[4];
    pack_stage(ws, xch, abt, b, k0, ntile, wave, lane, oc0, oc1, w);
    for (int k = k0; k < k1; k++) {
        __syncthreads();   // all reads of sl from k-1 complete
        *(ushort4_t*)&sl[l15 * 264 + oc0] = w[0];
        *(ushort4_t*)&sl[(16 + l15) * 264 + oc0] = w[1];
        *(ushort4_t*)&sl[l15 * 264 + oc1] = w[2];
        *(ushort4_t*)&sl[(16 + l15) * 264 + oc1] = w[3];
        __syncthreads();   // writes visible
        if (k + 1 < k1)
            pack_stage(ws, xch, abt, b, k + 1, ntile, wave, lane, oc0, oc1, w);
        // GEMM1: A-frags from fragment-ordered dt2 (coalesced)
        const ushort_t* dwb = dt + ((long)(k * 8 + wave) * 16) * 512 + lane * 8;
        #pragma unroll
        for (int s = 0; s < 8; s++) {
            int i0 = s * 32 + quad * 8;
            bf16x8 A0 = *(const bf16x8*)(dwb + s * 1024);
            bf16x8 A1 = *(const bf16x8*)(dwb + s * 1024 + 512);
            bf16x8 B0 = *(const bf16x8*)&sl[l15 * 264 + i0];
            bf16x8 B1 = *(const bf16x8*)&sl[(16 + l15) * 264 + i0];
            a00 = __builtin_amdgcn_mfma_f32_16x16x32_bf16(A0, B0, a00, 0, 0, 0);
            a01 = __builtin_amdgcn_mfma_f32_16x16x32_bf16(A0, B1, a01, 0, 0, 0);
            a10 = __builtin_amdgcn_mfma_f32_16x16x32_bf16(A1, B0, a10, 0, 0, 0);
            a11 = __builtin_amdgcn_mfma_f32_16x16x32_bf16(A1, B1, a11, 0, 0, 0);
        }
    }
    // fragment-order pacc store: slot = {a00,a01,a10,a11}, lane-contiguous
    float* pp = pacc + ((((long)(kh * 8 + b) * 32 + ntile) * 8 + wave) * 4) * 256 + lane * 4;
    *(float4*)(pp + 0)   = make_float4(a00[0], a00[1], a00[2], a00[3]);
    *(float4*)(pp + 256) = make_float4(a01[0], a01[1], a01[2], a01[3]);
    *(float4*)(pp + 512) = make_float4(a10[0], a10[1], a10[2], a10[3]);
    *(float4*)(pp + 768) = make_float4(a11[0], a11[1], a11[2], a11[3]);
}

// ==== k_final2: sum 2 partials -> bias+gelu -> GEMM2 -> z, 32n tile ====
__global__ __launch_bounds__(512, 2) void k_final2(
        const float* __restrict__ ws, const float* __restrict__ pacc,
        const float* __restrict__ comb_b1, const float* __restrict__ comb_b2,
        float* __restrict__ out) {
    int ntile = blockIdx.x, b = blockIdx.y;  // 32 x 8
    int n0 = ntile * 32;
    int tid = threadIdx.x;
    int lane = tid & 63, wave = tid >> 6;
    int l15 = lane & 15, quad = lane >> 4;
    int wq0 = wave * 32;
    __shared__ ushort_t sh2[32 * 296];
    const ushort_t* w2e = (const ushort_t*)(ws + OFF_W2E);
    int oc0 = wq0 + quad * 4, oc1 = oc0 + 16;
    // fragment-order pacc loads (same mapping as k_final1's store)
    const float* p0 = pacc + ((((long)(0 * 8 + b) * 32 + ntile) * 8 + wave) * 4) * 256 + lane * 4;
    const float* p1 = pacc + ((((long)(1 * 8 + b) * 32 + ntile) * 8 + wave) * 4) * 256 + lane * 4;
    float4 s00 = f4add(*(const float4*)(p0 + 0),   *(const float4*)(p1 + 0));
    float4 s01 = f4add(*(const float4*)(p0 + 256), *(const float4*)(p1 + 256));
    float4 s10 = f4add(*(const float4*)(p0 + 512), *(const float4*)(p1 + 512));
    float4 s11 = f4add(*(const float4*)(p0 + 768), *(const float4*)(p1 + 768));
    float4 bc0 = *(const float4*)&comb_b1[oc0];
    float4 bc1 = *(const float4*)&comb_b1[oc1];
    #pragma unroll
    for (int k = 0; k < K_; k++) {
        bc0 = f4add(bc0, *(const float4*)&ws[OFF_BC + k * 256 + oc0]);
        bc1 = f4add(bc1, *(const float4*)&ws[OFF_BC + k * 256 + oc1]);
    }
    *(ushort4_t*)&sh2[l15 * 296 + oc0]        = pack4f(s00, bc0);
    *(ushort4_t*)&sh2[(16 + l15) * 296 + oc0] = pack4f(s01, bc0);
    *(ushort4_t*)&sh2[l15 * 296 + oc1]        = pack4f(s10, bc1);
    *(ushort4_t*)&sh2[(16 + l15) * 296 + oc1] = pack4f(s11, bc1);
    {
        int row = tid >> 4, cc = tid & 15;  // 32 rows x 16 c
        float xv = ws[OFF_XW + ((long)b * N_ + n0 + row) * C_ + cc];
        sh2[row * 296 + 256 + cc] = f2bf(xv);
        sh2[row * 296 + 272 + cc] = 0;
    }
    __syncthreads();
    // GEMM2 swapped: D[q2][n] = w2e x Uext^T
    f32x4 h00 = {}, h01 = {}, h10 = {}, h11 = {};
    #pragma unroll
    for (int s = 0; s < 9; s++) {
        int i0 = s * 32 + quad * 8;
        bf16x8 A0 = *(const bf16x8*)&w2e[(wq0 + l15) * 288 + i0];
        bf16x8 A1 = *(const bf16x8*)&w2e[(wq0 + 16 + l15) * 288 + i0];
        bf16x8 B0 = *(const bf16x8*)&sh2[l15 * 296 + i0];
        bf16x8 B1 = *(const bf16x8*)&sh2[(16 + l15) * 296 + i0];
        h00 = __builtin_amdgcn_mfma_f32_16x16x32_bf16(A0, B0, h00, 0, 0, 0);
        h01 = __builtin_amdgcn_mfma_f32_16x16x32_bf16(A0, B1, h01, 0, 0, 0);
        h10 = __builtin_amdgcn_mfma_f32_16x16x32_bf16(A1, B0, h10, 0, 0, 0);
        h11 = __builtin_amdgcn_mfma_f32_16x16x32_bf16(A1, B1, h11, 0, 0, 0);
    }
    float4 zc0 = *(const float4*)&ws[OFF_ZWC + b * 256 + oc0];
    float4 zc1 = *(const float4*)&ws[OFF_ZWC + b * 256 + oc1];
    float4 cb0 = *(const float4*)&comb_b2[oc0];
    float4 cb1 = *(const float4*)&comb_b2[oc1];
    long ob = ((long)b * N_ + n0) << 8;
    float4 o00, o01, o10, o11;
    o00.x = zc0.x + 0.3f * (h00[0] + cb0.x); o00.y = zc0.y + 0.3f * (h00[1] + cb0.y);
    o00.z = zc0.z + 0.3f * (h00[2] + cb0.z); o00.w = zc0.w + 0.3f * (h00[3] + cb0.w);
    o01.x = zc0.x + 0.3f * (h01[0] + cb0.x); o01.y = zc0.y + 0.3f * (h01[1] + cb0.y);
    o01.z = zc0.z + 0.3f * (h01[2] + cb0.z); o01.w = zc0.w + 0.3f * (h01[3] + cb0.w);
    o10.x = zc1.x + 0.3f * (h10[0] + cb1.x); o10.y = zc1.y + 0.3f * (h10[1] + cb1.y);
    o10.z = zc1.z + 0.3f * (h10[2] + cb1.z); o10.w = zc1.w + 0.3f * (h10[3] + cb1.w);
    o11.x = zc1.x + 0.3f * (h11[0] + cb1.x); o11.y = zc1.y + 0.3f * (h11[1] + cb1.y);
    o11.z = zc1.z + 0.3f * (h11[2] + cb1.z); o11.w = zc1.w + 0.3f * (h11[3] + cb1.w);
    *(float4*)&out[ob + ((long)l15 << 8) + oc0] = o00;
    *(float4*)&out[ob + ((long)(16 + l15) << 8) + oc0] = o01;
    *(float4*)&out[ob + ((long)l15 << 8) + oc1] = o10;
    *(float4*)&out[ob + ((long)(16 + l15) << 8) + oc1] = o11;
}

extern "C" void kernel_launch(void* const* d_in, const int* in_sizes, int n_in,
                              void* d_out, int out_size, void* d_ws, size_t ws_size,
                              hipStream_t stream) {
    const float* x = (const float*)d_in[0];
    const float* in_proj_w = (const float*)d_in[1];
    const float* in_proj_b = (const float*)d_in[2];
    const float* pe_w1 = (const float*)d_in[3];
    const float* pe_b1 = (const float*)d_in[4];
    const float* pe_w2 = (const float*)d_in[5];
    const float* pe_b2 = (const float*)d_in[6];
    const float* noise_w = (const float*)d_in[7];
    const float* noise_b = (const float*)d_in[8];
    const float* sfe_w1 = (const float*)d_in[9];
    const float* sfe_b1 = (const float*)d_in[10];
    const float* sfe_w2 = (const float*)d_in[11];
    const float* sfe_b2 = (const float*)d_in[12];
    const float* comb_w1 = (const float*)d_in[13];
    const float* comb_b1 = (const float*)d_in[14];
    const float* comb_w2 = (const float*)d_in[15];
    const float* comb_b2 = (const float*)d_in[16];
    const float* pool_param = (const float*)d_in[17];
    float* ws = (float*)d_ws;
    float* out = (float*)d_out;

    hipLaunchKernelGGL(k_stage1, dim3(896), dim3(256), 0, stream, x, ws);
    hipLaunchKernelGGL(k_stage2, dim3(200), dim3(128), 0, stream,
                       pool_param, pe_w1, pe_b1, pe_w2, pe_b2, noise_w, noise_b, in_proj_b, ws);
    hipLaunchKernelGGL(k_stage3, dim3(576), dim3(256), 0, stream,
                       in_proj_b, in_proj_w, sfe_w1, sfe_w2, sfe_b2, comb_w1, comb_w2, ws, out);
    hipLaunchKernelGGL(k_stage4, dim3(629), dim3(256), 0, stream, sfe_w1, sfe_b1, ws);
    hipLaunchKernelGGL(k_final1, dim3(32, 8, 2), dim3(512), 0, stream,
                       ws, (const ushort_t*)(ws + OFF_XC), (const ushort_t*)(ws + OFF_AB),
                       ws + OFF_PACC);
    hipLaunchKernelGGL(k_final2, dim3(32, 8), dim3(512), 0, stream,
                       ws, ws + OFF_PACC, comb_b1, comb_b2, out);
}

// Round 13
// 220.379 us; speedup vs baseline: 1.6068x; 1.0873x over previous
//
#include <hip/hip_runtime.h>
#include <hip/hip_bf16.h>
#include <math.h>

#define B_ 8
#define P_ 24
#define N_ 1024
#define C_ 16
#define D_ 256
#define K_ 13

// workspace offsets (in floats)
#define OFF_SM   0          // spatial_mean: 192*16
#define OFF_DLP  4096       // d_lag partials: 8*4*24*4chunks = 3072
#define OFF_ATT  8192       // att: 8*24
#define OFF_GAM  9216       // gamma: 8*32 (re[13] @ +0, im[13] @ +16)
#define OFF_TE   12288      // te_fold: 192*256
#define OFF_FTR  65536      // Fte_re: 8*13*256
#define OFF_FTI  94208      // Fte_im
#define OFF_ZWC  122880     // zw_const: 8*256
#define OFF_AB   126976     // ABt bf16 FRAGMENT order [k][wave][half][lane][8]
#define OFF_BC   266240     // bias_comb: 13*256
#define OFF_DD   270336     // Dt bf16 FRAGMENT order [k][wave][s][half][lane][8]
#define OFF_W2E  696320     // W2ext bf16 [q2][288]
#define OFF_XC   1126400    // Xhat bf16 FRAGMENT order [b][k][nt32][half][lane][8]
#define OFF_XW   2830336    // xw fp32: 8*1024*16
#define OFF_ABP  3000000    // AB partials fp32 [k][et][32ch][256o]
#define OFF_C1P  3900000    // c1 partials fp32 [b][k][8ec][256]
#define OFF_PACC 4194304    // GEMM1 split-k partials fp32, fragment order

typedef unsigned short ushort_t;
typedef __bf16 bf16x8 __attribute__((ext_vector_type(8)));
typedef float f32x4 __attribute__((ext_vector_type(4)));
typedef unsigned short ushort4_t __attribute__((ext_vector_type(4)));

__device__ __forceinline__ float gelu_f(float v) {
    return 0.5f * v * (1.0f + erff(v * 0.70710678118654752440f));
}
__device__ __forceinline__ float softplus_f(float z) {
    return fmaxf(z, 0.0f) + log1pf(expf(-fabsf(z)));
}
__device__ __forceinline__ ushort_t f2bf(float f) {
    union { float f; unsigned u; } v; v.f = f;
    unsigned r = v.u + 0x7fffu + ((v.u >> 16) & 1u);
    return (ushort_t)(r >> 16);
}
__device__ __forceinline__ float bf2f(ushort_t h) {
    union { unsigned u; float f; } v; v.u = ((unsigned)h) << 16;
    return v.f;
}
__device__ __forceinline__ float4 f4add(float4 a, float4 b) {
    a.x += b.x; a.y += b.y; a.z += b.z; a.w += b.w; return a;
}
__device__ __forceinline__ ushort4_t pack4(f32x4 v, float4 c) {
    ushort4_t w;
    w.x = f2bf(gelu_f(v[0] + c.x));
    w.y = f2bf(gelu_f(v[1] + c.y));
    w.z = f2bf(gelu_f(v[2] + c.z));
    w.w = f2bf(gelu_f(v[3] + c.w));
    return w;
}
__device__ __forceinline__ ushort4_t pack4f(float4 v, float4 c) {
    ushort4_t w;
    w.x = f2bf(gelu_f(v.x + c.x));
    w.y = f2bf(gelu_f(v.y + c.y));
    w.z = f2bf(gelu_f(v.z + c.z));
    w.w = f2bf(gelu_f(v.w + c.w));
    return w;
}
__device__ __forceinline__ void lag_one(const float* xs, int t,
        float& s1, float& s2, float& s4, float& s6) {
    float xr[7];
    #pragma unroll
    for (int jj = 0; jj < 7; jj++) {
        int s = t - jj;
        float xt = xs[jj];
        xr[jj] = (s <= 0) ? 0.f
               : (s == 1) ? (xt - xs[jj + 1])
               : (xt - (xt + xs[jj + 1] + xs[jj + 2]) * (1.0f / 3.0f));
    }
    if (t >= 1) s1 += fabsf(xr[0] - xr[1]);
    if (t >= 2) s2 += fabsf(xr[0] - xr[2]);
    if (t >= 4) s4 += fabsf(xr[0] - xr[4]);
    if (t >= 6) s6 += fabsf(xr[0] - xr[6]);
}

// ==== A: lag(768) + xhat(512) + prep_d(208) + ab_part(104) + mean(192) + w2e(256) ====
// All branches independent (x-work + weight-prep) -> weight-prep overlaps the
// latency-bound x streaming instead of serializing behind stages 1-2.
__global__ void k_A(const float* __restrict__ x, const float* __restrict__ in_proj_w,
                    const float* __restrict__ sfe_w1, const float* __restrict__ sfe_w2,
                    const float* __restrict__ sfe_b2, const float* __restrict__ comb_w1,
                    const float* __restrict__ comb_w2, float* __restrict__ ws) {
    __shared__ __align__(16) char smem[8448];
    int bx = blockIdx.x, tid = threadIdx.x;
    if (bx < 768) {
        // lag distances, 4-way idx-chunk split, float4 loads
        int t = bx % P_;
        int rb = bx / P_;
        int b = rb & 7, chunk = rb >> 3;
        const float* xp = x + (long)b * P_ * N_ * C_;
        float s1 = 0.f, s2 = 0.f, s4 = 0.f, s6 = 0.f;
        int idx4 = chunk * 1024 + tid;
        #pragma unroll
        for (int it = 0; it < 4; it++, idx4 += 256) {
            float4 xv[9];
            #pragma unroll
            for (int jj = 0; jj < 9; jj++)
                xv[jj] = (t - jj >= 0)
                    ? *(const float4*)&xp[(long)(t - jj) * (N_ * C_) + (idx4 << 2)]
                    : make_float4(0.f, 0.f, 0.f, 0.f);
            float xs0[9], xs1[9], xs2[9], xs3[9];
            #pragma unroll
            for (int jj = 0; jj < 9; jj++) {
                xs0[jj] = xv[jj].x; xs1[jj] = xv[jj].y;
                xs2[jj] = xv[jj].z; xs3[jj] = xv[jj].w;
            }
            lag_one(xs0, t, s1, s2, s4, s6);
            lag_one(xs1, t, s1, s2, s4, s6);
            lag_one(xs2, t, s1, s2, s4, s6);
            lag_one(xs3, t, s1, s2, s4, s6);
        }
        float4* red = (float4*)smem;
        red[tid] = make_float4(s1, s2, s4, s6);
        __syncthreads();
        for (int st = 128; st > 0; st >>= 1) {
            if (tid < st) red[tid] = f4add(red[tid], red[tid + st]);
            __syncthreads();
        }
        if (tid == 0) {
            ws[OFF_DLP + ((b * 4 + 0) * P_ + t) * 4 + chunk] = red[0].x;
            ws[OFF_DLP + ((b * 4 + 1) * P_ + t) * 4 + chunk] = red[0].y;
            ws[OFF_DLP + ((b * 4 + 2) * P_ + t) * 4 + chunk] = red[0].z;
            ws[OFF_DLP + ((b * 4 + 3) * P_ + t) * 4 + chunk] = red[0].w;
        }
    } else if (bx < 1280) {
        // xhat DFT -> fragment-ordered xc2
        int j = bx - 768;
        int ntile = j & 63, b = j >> 6;
        float* ct = (float*)smem;
        float* st = ct + K_ * P_;
        int n = ntile * 16 + (tid >> 4), c = tid & 15;
        for (int i = tid; i < K_ * P_; i += 256) {
            int k = i / P_, t = i % P_;
            int r = (k * t) % P_;
            float ph = 6.283185307179586f * (float)r / (float)P_;
            ct[i] = cosf(ph);
            st[i] = sinf(ph);
        }
        __syncthreads();
        float re[K_], im[K_];
        #pragma unroll
        for (int k = 0; k < K_; k++) { re[k] = 0.f; im[k] = 0.f; }
        for (int t = 0; t < P_; t++) {
            float v = x[((long)(b * P_ + t) * N_ + n) * C_ + c];
            #pragma unroll
            for (int k = 0; k < K_; k++) {
                re[k] += ct[k * P_ + t] * v;
                im[k] -= st[k * P_ + t] * v;
            }
        }
        ushort_t* xcp = (ushort_t*)(ws + OFF_XC);
        int nt32 = n >> 5, halfn = (n >> 4) & 1, l15n = n & 15;
        int lre = ((c >> 3) * 16 + l15n) * 8 + (c & 7);
        int lim = ((2 + (c >> 3)) * 16 + l15n) * 8 + (c & 7);
        #pragma unroll
        for (int k = 0; k < K_; k++) {
            long base = ((((long)(b * K_ + k) * 32 + nt32) * 2 + halfn) * 64) * 8;
            xcp[base + lre] = f2bf(re[k]);
            xcp[base + lim] = f2bf(im[k]);
        }
    } else if (bx < 1488) {
        // prep_d (16-wide K-steps, 8.4KB LDS) -> fragment-ordered Dt + BC
        int j = bx - 1280;
        int qt0 = (j & 3) * 64, it0 = ((j >> 2) & 3) * 64, k = j >> 4;
        float* As = (float*)smem;        // 64*17
        float* Bs = As + 64 * 17;        // 16*64
        int tq = tid & 15, ti = tid >> 4;
        float acc[4][4];
        #pragma unroll
        for (int r = 0; r < 4; r++)
            #pragma unroll
            for (int c = 0; c < 4; c++) acc[r][c] = 0.f;
        float bias = 0.f;
        for (int step = 0; step < 16; step++) {
            int ob = step * 16;
            __syncthreads();
            #pragma unroll
            for (int u = 0; u < 4; u++) {
                int idx = u * 256 + tid;
                int i = idx >> 4, o = idx & 15;
                As[i * 17 + o] = sfe_w2[((long)(k * 256 + it0 + i) << 8) + ob + o];
            }
            #pragma unroll
            for (int u = 0; u < 4; u++) {
                int idx = u * 256 + tid;
                int o = idx >> 6, q = idx & 63;
                Bs[o * 64 + q] = comb_w1[((long)(k * 256 + ob + o) << 8) + qt0 + q];
            }
            __syncthreads();
            if (it0 == 0 && tid < 64) {
                #pragma unroll
                for (int o = 0; o < 16; o++)
                    bias += sfe_b2[k * 256 + ob + o] * Bs[o * 64 + tid];
            }
            #pragma unroll 4
            for (int o = 0; o < 16; o++) {
                const float4 bv = *(const float4*)&Bs[o * 64 + tq * 4];
                float a[4];
                #pragma unroll
                for (int r = 0; r < 4; r++) a[r] = As[(ti * 4 + r) * 17 + o];
                #pragma unroll
                for (int r = 0; r < 4; r++) {
                    acc[r][0] += a[r] * bv.x;
                    acc[r][1] += a[r] * bv.y;
                    acc[r][2] += a[r] * bv.z;
                    acc[r][3] += a[r] * bv.w;
                }
            }
        }
        ushort_t* dtp = (ushort_t*)(ws + OFF_DD);
        #pragma unroll
        for (int c = 0; c < 4; c++)
            #pragma unroll
            for (int r = 0; r < 4; r++) {
                int q = qt0 + tq * 4 + c, i = it0 + ti * 4 + r;
                int wv = q >> 5, hf = (q >> 4) & 1, l = q & 15;
                int s = i >> 5, qd = (i >> 3) & 3, jj = i & 7;
                long idx = ((((long)(k * 8 + wv) * 8 + s) * 2 + hf) * 64 + qd * 16 + l) * 8 + jj;
                dtp[idx] = f2bf(acc[r][c]);
            }
        if (it0 == 0 && tid < 64)
            ws[OFF_BC + k * 256 + qt0 + tid] = bias;
    } else if (bx < 1592) {
        // ab_part
        int j = bx - 1488;
        int k = j >> 3, et = j & 7;
        int o = tid;
        float accA[C_], accB[C_];
        #pragma unroll
        for (int c = 0; c < C_; c++) { accA[c] = 0.f; accB[c] = 0.f; }
        const float* w1r = sfe_w1 + (long)k * 512 * 256;
        const float* w1i = w1r + 256 * 256;
        for (int e = et * 32; e < et * 32 + 32; e++) {
            float vr = w1r[e * 256 + o];
            float vi = w1i[e * 256 + o];
            #pragma unroll
            for (int c = 0; c < C_; c++) {
                float w = in_proj_w[c * 256 + e];
                accA[c] += w * vr;
                accB[c] += w * vi;
            }
        }
        float* abp = ws + OFF_ABP + (long)((k * 8 + et) * 32) * 256;
        #pragma unroll
        for (int c = 0; c < C_; c++) {
            abp[c * 256 + o] = accA[c];
            abp[(16 + c) * 256 + o] = accB[c];
        }
    } else if (bx < 1784) {
        // spatial mean
        float* lds = (float*)smem;
        int bt = bx - 1592;
        int c = tid & 15, ns = tid >> 4;
        const float* xp = x + (long)bt * (N_ * C_);
        float s = 0.f;
        for (int n = ns; n < N_; n += 16) s += xp[n * C_ + c];
        lds[tid] = s;
        __syncthreads();
        for (int st = 128; st >= 16; st >>= 1) {
            if (tid < st) lds[tid] += lds[tid + st];
            __syncthreads();
        }
        if (tid < 16) ws[OFF_SM + bt * 16 + tid] = lds[tid] * (1.0f / 1024.0f);
    } else {
        // W2ext
        int q2 = bx - 1784;
        ushort_t* w2e = (ushort_t*)(ws + OFF_W2E);
        for (int i = tid; i < 288; i += 256) {
            float v = 0.f;
            if (i < 256) v = comb_w2[(i << 8) + q2];
            else if (i < 272) v = in_proj_w[((i - 256) << 8) + q2] * (1.0f / 0.3f);
            w2e[q2 * 288 + i] = f2bf(v);
        }
    }
}

// ==== B: gating+gamma (8 blocks) + time_emb (192 blocks), 128 thr ====
__global__ void k_B(const float* __restrict__ pool_param,
                    const float* __restrict__ pe_w1, const float* __restrict__ pe_b1,
                    const float* __restrict__ pe_w2, const float* __restrict__ pe_b2,
                    const float* __restrict__ noise_w, const float* __restrict__ noise_b,
                    const float* __restrict__ in_proj_b, float* __restrict__ ws) {
    __shared__ float sm[256];
    int bx = blockIdx.x, tid = threadIdx.x;
    if (bx < 8) {
        int b = bx;
        float* d = sm; float* ad = sm + 96; float* med = sm + 192; float* mad = sm + 196;
        float* attb = sm + 200; float* gbuf = sm + 224;
        int li = tid / P_, t = tid - li * P_;
        bool active = tid < 4 * P_;
        if (active) {
            const float* dp = ws + OFF_DLP + ((b * 4 + li) * P_ + t) * 4;
            d[li * P_ + t] = (dp[0] + dp[1] + dp[2] + dp[3]) * (1.0f / (N_ * C_));
        }
        __syncthreads();
        if (active) {
            float v = d[li * P_ + t];
            int rank = 0;
            #pragma unroll
            for (int jj = 0; jj < P_; jj++) {
                float dj = d[li * P_ + jj];
                rank += (dj < v || (dj == v && jj < t)) ? 1 : 0;
            }
            if (rank == 11) med[li] = v;
        }
        __syncthreads();
        if (active) ad[li * P_ + t] = fabsf(d[li * P_ + t] - med[li]);
        __syncthreads();
        if (active) {
            float v = ad[li * P_ + t];
            int rank = 0;
            #pragma unroll
            for (int jj = 0; jj < P_; jj++) {
                float dj = ad[li * P_ + jj];
                rank += (dj < v || (dj == v && jj < t)) ? 1 : 0;
            }
            if (rank == 11) mad[li] = v;
        }
        __syncthreads();
        if (active) {
            float z = (d[li * P_ + t] - med[li]) / (mad[li] * 1.4826f + 1e-6f);
            ad[li * P_ + t] = softplus_f(z);
        }
        __syncthreads();
        if (tid == 0) {
            float g[P_];
            #pragma unroll
            for (int tt = 0; tt < P_; tt++)
                g[tt] = 0.25f * (ad[tt] + ad[P_ + tt] + ad[2 * P_ + tt] + ad[3 * P_ + tt]);
            float c = g[0];
            gbuf[0] = g[0];
            for (int tt = 1; tt < P_; tt++) { c = 0.6f * c + 0.4f * g[tt]; gbuf[tt] = c; }
            float mean = 0.f;
            for (int tt = 0; tt < P_; tt++) mean += gbuf[tt];
            mean *= (1.0f / P_);
            float gate[P_];
            #pragma unroll
            for (int tt = 0; tt < P_; tt++) gate[tt] = 1.0f / (1.0f + expf(-1.5f * (gbuf[tt] - mean)));
            float m = -1e30f;
            float pp[P_];
            #pragma unroll
            for (int tt = 0; tt < P_; tt++) { pp[tt] = pool_param[tt]; m = fmaxf(m, pp[tt]); }
            float ssum = 0.f;
            #pragma unroll
            for (int tt = 0; tt < P_; tt++) { pp[tt] = expf(pp[tt] - m); ssum += pp[tt]; }
            float m2 = -1e30f;
            #pragma unroll
            for (int tt = 0; tt < P_; tt++) { pp[tt] = (pp[tt] / ssum) * (1.0f + gate[tt]); m2 = fmaxf(m2, pp[tt]); }
            float s2 = 0.f;
            #pragma unroll
            for (int tt = 0; tt < P_; tt++) { pp[tt] = expf(pp[tt] - m2); s2 += pp[tt]; }
            #pragma unroll
            for (int tt = 0; tt < P_; tt++) {
                float a = pp[tt] / s2;
                ws[OFF_ATT + b * P_ + tt] = a;
                attb[tt] = a;
            }
        }
        __syncthreads();
        if (tid < K_) {
            int k = tid;
            float cre = 0.f, cim = 0.f;
            for (int t2 = 0; t2 < P_; t2++) {
                int r = (k * t2) % P_;
                float ph = 6.283185307179586f * (float)r / (float)P_;
                float a = attb[t2];
                cre += a * cosf(ph);
                cim += a * sinf(ph);
            }
            float w = (k == 0 || k == 12) ? 1.0f : 2.0f;
            ws[OFF_GAM + b * 32 + k] = (w / 24.0f) * cre;
            ws[OFF_GAM + b * 32 + 16 + k] = -(w / 24.0f) * cim;
        }
    } else {
        int bt = bx - 8;
        int t = bt % P_;
        int k = tid >> 6, o = tid & 63;
        float* p1e = sm;
        float period = (k == 0) ? 24.0f : 72.0f;
        float ph = 6.283185307179586f * (float)t / period;
        float sv = sinf(ph), cv = cosf(ph);
        float v = sv * pe_w1[(k * 2 + 0) * 64 + o] + cv * pe_w1[(k * 2 + 1) * 64 + o] + pe_b1[k * 64 + o];
        p1e[tid] = gelu_f(v);
        __syncthreads();
        float acc = pe_b2[k * 64 + o];
        for (int i = 0; i < 64; i++) acc += p1e[k * 64 + i] * pe_w2[(k * 64 + i) * 64 + o];
        ws[OFF_TE + bt * D_ + tid] = acc + in_proj_b[tid];
        float nacc = noise_b[tid];
        for (int c = 0; c < C_; c++) nacc += ws[OFF_SM + bt * C_ + c] * noise_w[c * 128 + tid];
        ws[OFF_TE + bt * D_ + 128 + tid] = nacc + in_proj_b[128 + tid];
    }
}

// ==== C: te_reduce(8) + ab_red(13), 256 thr ====
__global__ void k_C(const float* __restrict__ in_proj_b, float* __restrict__ ws,
                    float* __restrict__ out) {
    __shared__ __align__(16) char smem[2608];
    int bx = blockIdx.x, tid = threadIdx.x;
    if (bx < 8) {
        int b = bx;
        float* ct = (float*)smem;
        float* st = ct + K_ * P_;
        float* attl = st + K_ * P_;
        for (int i = tid; i < K_ * P_; i += 256) {
            int k = i / P_, t = i % P_;
            int r = (k * t) % P_;
            float ph = 6.283185307179586f * (float)r / (float)P_;
            ct[i] = cosf(ph);
            st[i] = sinf(ph);
        }
        if (tid < P_) attl[tid] = ws[OFF_ATT + b * P_ + tid];
        __syncthreads();
        float fre[K_], fim[K_];
        #pragma unroll
        for (int k = 0; k < K_; k++) { fre[k] = 0.f; fim[k] = 0.f; }
        float smn = 0.f, sa = 0.f;
        for (int t = 0; t < P_; t++) {
            float v = ws[OFF_TE + (b * P_ + t) * D_ + tid];
            smn += v;
            sa += attl[t] * v;
            #pragma unroll
            for (int k = 0; k < K_; k++) {
                fre[k] += ct[k * P_ + t] * v;
                fim[k] -= st[k * P_ + t] * v;
            }
        }
        out[2097152 + b * D_ + tid] = smn * (1.0f / P_) - in_proj_b[tid];
        ws[OFF_ZWC + b * D_ + tid] = sa;
        #pragma unroll
        for (int k = 0; k < K_; k++) {
            ws[OFF_FTR + (b * K_ + k) * D_ + tid] = fre[k];
            ws[OFF_FTI + (b * K_ + k) * D_ + tid] = fim[k];
        }
    } else {
        // reduce AB partials -> ABt fragment order [k][wave][half][lane][8]
        int k = bx - 8, o = tid;
        ushort_t* abt = (ushort_t*)(ws + OFF_AB);
        const float* base = ws + OFF_ABP + (long)(k * 8 * 32) * 256;
        int wv = o >> 5, hf = (o >> 4) & 1, l = o & 15;
        long obase = (((long)(k * 8 + wv) * 2 + hf) * 64) * 8;
        #pragma unroll
        for (int ch = 0; ch < 32; ch++) {
            float s = 0.f;
            #pragma unroll
            for (int et = 0; et < 8; et++) s += base[(et * 32 + ch) * 256 + o];
            abt[obase + ((ch >> 3) * 16 + l) * 8 + (ch & 7)] = f2bf(s);
        }
    }
}

// ==== D: c1(104) + xw-from-xc2(512), 256 thr ====
__global__ void k_D(const float* __restrict__ sfe_w1, const float* __restrict__ sfe_b1,
                    float* __restrict__ ws) {
    __shared__ __align__(16) char smem[2608];
    int bx = blockIdx.x, tid = threadIdx.x;
    if (bx < 104) {
        int k = bx >> 3, ec = bx & 7;
        float* F = (float*)smem;  // [8b][64c]
        for (int i = tid; i < 512; i += 256) {
            int bb = i >> 6, cc = i & 63;
            int cg = ec * 64 + cc;
            F[i] = (cg < 256) ? ws[OFF_FTR + (bb * K_ + k) * D_ + cg]
                              : ws[OFF_FTI + (bb * K_ + k) * D_ + cg - 256];
        }
        __syncthreads();
        int o = tid;
        float acc[8];
        float b1 = (ec == 0) ? sfe_b1[k * 256 + o] : 0.f;
        #pragma unroll
        for (int bb = 0; bb < 8; bb++) acc[bb] = b1;
        const float* w1 = sfe_w1 + (long)k * 512 * 256 + (long)(ec * 64) * 256;
        for (int c = 0; c < 64; c++) {
            float w = w1[c * 256 + o];
            #pragma unroll
            for (int bb = 0; bb < 8; bb++) acc[bb] += F[bb * 64 + c] * w;
        }
        #pragma unroll
        for (int bb = 0; bb < 8; bb++)
            ws[OFF_C1P + (long)(((bb * K_ + k) * 8) + ec) * 256 + o] = acc[bb];
    } else {
        int j = bx - 104;
        int ntile = j & 63, b = j >> 6;
        int n = ntile * 16 + (tid >> 4), c = tid & 15;
        float gre[K_], gim[K_];
        #pragma unroll
        for (int k = 0; k < K_; k++) {
            gre[k] = ws[OFF_GAM + b * 32 + k];
            gim[k] = ws[OFF_GAM + b * 32 + 16 + k];
        }
        const ushort_t* xcp = (const ushort_t*)(ws + OFF_XC);
        int nt32 = n >> 5, halfn = (n >> 4) & 1, l15n = n & 15;
        int lre = ((c >> 3) * 16 + l15n) * 8 + (c & 7);
        int lim = ((2 + (c >> 3)) * 16 + l15n) * 8 + (c & 7);
        float acc = 0.f;
        #pragma unroll
        for (int k = 0; k < K_; k++) {
            long base = ((((long)(b * K_ + k) * 32 + nt32) * 2 + halfn) * 64) * 8;
            acc += gre[k] * bf2f(xcp[base + lre]) + gim[k] * bf2f(xcp[base + lim]);
        }
        ws[OFF_XW + ((long)b * N_ + n) * C_ + c] = acc;
    }
}

// pack-stage for one k: coalesced fragment loads + p-MFMA + gelu-pack
__device__ __forceinline__ void pack_stage(
        const float* __restrict__ ws, const ushort_t* __restrict__ xch,
        const ushort_t* __restrict__ abt, int b, int kk, int ntile,
        int wave, int lane, int oc0, int oc1, ushort4_t* w) {
    const ushort_t* xb = xch + (((long)(b * K_ + kk) * 32 + ntile) * 2) * 512 + lane * 8;
    bf16x8 pa0 = *(const bf16x8*)xb;
    bf16x8 pa1 = *(const bf16x8*)(xb + 512);
    const ushort_t* ab = abt + ((long)(kk * 8 + wave) * 2) * 512 + lane * 8;
    bf16x8 pb0 = *(const bf16x8*)ab;
    bf16x8 pb1 = *(const bf16x8*)(ab + 512);
    float4 c10 = make_float4(0.f, 0.f, 0.f, 0.f), c11 = c10;
    #pragma unroll
    for (int ec = 0; ec < 8; ec++) {
        const float* cp = ws + OFF_C1P + (long)(((b * K_ + kk) * 8) + ec) * 256;
        c10 = f4add(c10, *(const float4*)&cp[oc0]);
        c11 = f4add(c11, *(const float4*)&cp[oc1]);
    }
    f32x4 p00 = {}, p01 = {}, p10 = {}, p11 = {};
    p00 = __builtin_amdgcn_mfma_f32_16x16x32_bf16(pb0, pa0, p00, 0, 0, 0);
    p01 = __builtin_amdgcn_mfma_f32_16x16x32_bf16(pb0, pa1, p01, 0, 0, 0);
    p10 = __builtin_amdgcn_mfma_f32_16x16x32_bf16(pb1, pa0, p10, 0, 0, 0);
    p11 = __builtin_amdgcn_mfma_f32_16x16x32_bf16(pb1, pa1, p11, 0, 0, 0);
    w[0] = pack4(p00, c10);
    w[1] = pack4(p01, c10);
    w[2] = pack4(p10, c11);
    w[3] = pack4(p11, c11);
}

// ==== k_final1: split-k(2) GEMM1 partial, 32n tile, coalesced fragment loads ====
__global__ __launch_bounds__(512, 4) void k_final1(
        const float* __restrict__ ws, const ushort_t* __restrict__ xch,
        const ushort_t* __restrict__ abt, float* __restrict__ pacc) {
    int ntile = blockIdx.x, b = blockIdx.y, kh = blockIdx.z;
    const int k0 = kh ? 7 : 0;
    const int k1 = kh ? K_ : 7;
    int tid = threadIdx.x;
    int lane = tid & 63, wave = tid >> 6;
    int l15 = lane & 15, quad = lane >> 4;
    int wq0 = wave * 32;
    __shared__ ushort_t sl[32 * 264];    // 16896 B
    const ushort_t* dt = (const ushort_t*)(ws + OFF_DD);
    int oc0 = wq0 + quad * 4, oc1 = oc0 + 16;
    f32x4 a00 = {}, a01 = {}, a10 = {}, a11 = {};
    ushort4_t w[4];
    pack_stage(ws, xch, abt, b, k0, ntile, wave, lane, oc0, oc1, w);
    for (int k = k0; k < k1; k++) {
        __syncthreads();
        *(ushort4_t*)&sl[l15 * 264 + oc0] = w[0];
        *(ushort4_t*)&sl[(16 + l15) * 264 + oc0] = w[1];
        *(ushort4_t*)&sl[l15 * 264 + oc1] = w[2];
        *(ushort4_t*)&sl[(16 + l15) * 264 + oc1] = w[3];
        __syncthreads();
        if (k + 1 < k1)
            pack_stage(ws, xch, abt, b, k + 1, ntile, wave, lane, oc0, oc1, w);
        const ushort_t* dwb = dt + ((long)(k * 8 + wave) * 16) * 512 + lane * 8;
        #pragma unroll
        for (int s = 0; s < 8; s++) {
            int i0 = s * 32 + quad * 8;
            bf16x8 A0 = *(const bf16x8*)(dwb + s * 1024);
            bf16x8 A1 = *(const bf16x8*)(dwb + s * 1024 + 512);
            bf16x8 B0 = *(const bf16x8*)&sl[l15 * 264 + i0];
            bf16x8 B1 = *(const bf16x8*)&sl[(16 + l15) * 264 + i0];
            a00 = __builtin_amdgcn_mfma_f32_16x16x32_bf16(A0, B0, a00, 0, 0, 0);
            a01 = __builtin_amdgcn_mfma_f32_16x16x32_bf16(A0, B1, a01, 0, 0, 0);
            a10 = __builtin_amdgcn_mfma_f32_16x16x32_bf16(A1, B0, a10, 0, 0, 0);
            a11 = __builtin_amdgcn_mfma_f32_16x16x32_bf16(A1, B1, a11, 0, 0, 0);
        }
    }
    float* pp = pacc + ((((long)(kh * 8 + b) * 32 + ntile) * 8 + wave) * 4) * 256 + lane * 4;
    *(float4*)(pp + 0)   = make_float4(a00[0], a00[1], a00[2], a00[3]);
    *(float4*)(pp + 256) = make_float4(a01[0], a01[1], a01[2], a01[3]);
    *(float4*)(pp + 512) = make_float4(a10[0], a10[1], a10[2], a10[3]);
    *(float4*)(pp + 768) = make_float4(a11[0], a11[1], a11[2], a11[3]);
}

// ==== k_final2: sum 2 partials -> bias+gelu -> GEMM2 -> z, 32n tile ====
__global__ __launch_bounds__(512, 2) void k_final2(
        const float* __restrict__ ws, const float* __restrict__ pacc,
        const float* __restrict__ comb_b1, const float* __restrict__ comb_b2,
        float* __restrict__ out) {
    int ntile = blockIdx.x, b = blockIdx.y;  // 32 x 8
    int n0 = ntile * 32;
    int tid = threadIdx.x;
    int lane = tid & 63, wave = tid >> 6;
    int l15 = lane & 15, quad = lane >> 4;
    int wq0 = wave * 32;
    __shared__ ushort_t sh2[32 * 296];
    const ushort_t* w2e = (const ushort_t*)(ws + OFF_W2E);
    int oc0 = wq0 + quad * 4, oc1 = oc0 + 16;
    const float* p0 = pacc + ((((long)(0 * 8 + b) * 32 + ntile) * 8 + wave) * 4) * 256 + lane * 4;
    const float* p1 = pacc + ((((long)(1 * 8 + b) * 32 + ntile) * 8 + wave) * 4) * 256 + lane * 4;
    float4 s00 = f4add(*(const float4*)(p0 + 0),   *(const float4*)(p1 + 0));
    float4 s01 = f4add(*(const float4*)(p0 + 256), *(const float4*)(p1 + 256));
    float4 s10 = f4add(*(const float4*)(p0 + 512), *(const float4*)(p1 + 512));
    float4 s11 = f4add(*(const float4*)(p0 + 768), *(const float4*)(p1 + 768));
    float4 bc0 = *(const float4*)&comb_b1[oc0];
    float4 bc1 = *(const float4*)&comb_b1[oc1];
    #pragma unroll
    for (int k = 0; k < K_; k++) {
        bc0 = f4add(bc0, *(const float4*)&ws[OFF_BC + k * 256 + oc0]);
        bc1 = f4add(bc1, *(const float4*)&ws[OFF_BC + k * 256 + oc1]);
    }
    *(ushort4_t*)&sh2[l15 * 296 + oc0]        = pack4f(s00, bc0);
    *(ushort4_t*)&sh2[(16 + l15) * 296 + oc0] = pack4f(s01, bc0);
    *(ushort4_t*)&sh2[l15 * 296 + oc1]        = pack4f(s10, bc1);
    *(ushort4_t*)&sh2[(16 + l15) * 296 + oc1] = pack4f(s11, bc1);
    {
        int row = tid >> 4, cc = tid & 15;
        float xv = ws[OFF_XW + ((long)b * N_ + n0 + row) * C_ + cc];
        sh2[row * 296 + 256 + cc] = f2bf(xv);
        sh2[row * 296 + 272 + cc] = 0;
    }
    __syncthreads();
    f32x4 h00 = {}, h01 = {}, h10 = {}, h11 = {};
    #pragma unroll
    for (int s = 0; s < 9; s++) {
        int i0 = s * 32 + quad * 8;
        bf16x8 A0 = *(const bf16x8*)&w2e[(wq0 + l15) * 288 + i0];
        bf16x8 A1 = *(const bf16x8*)&w2e[(wq0 + 16 + l15) * 288 + i0];
        bf16x8 B0 = *(const bf16x8*)&sh2[l15 * 296 + i0];
        bf16x8 B1 = *(const bf16x8*)&sh2[(16 + l15) * 296 + i0];
        h00 = __builtin_amdgcn_mfma_f32_16x16x32_bf16(A0, B0, h00, 0, 0, 0);
        h01 = __builtin_amdgcn_mfma_f32_16x16x32_bf16(A0, B1, h01, 0, 0, 0);
        h10 = __builtin_amdgcn_mfma_f32_16x16x32_bf16(A1, B0, h10, 0, 0, 0);
        h11 = __builtin_amdgcn_mfma_f32_16x16x32_bf16(A1, B1, h11, 0, 0, 0);
    }
    float4 zc0 = *(const float4*)&ws[OFF_ZWC + b * 256 + oc0];
    float4 zc1 = *(const float4*)&ws[OFF_ZWC + b * 256 + oc1];
    float4 cb0 = *(const float4*)&comb_b2[oc0];
    float4 cb1 = *(const float4*)&comb_b2[oc1];
    long ob = ((long)b * N_ + n0) << 8;
    float4 o00, o01, o10, o11;
    o00.x = zc0.x + 0.3f * (h00[0] + cb0.x); o00.y = zc0.y + 0.3f * (h00[1] + cb0.y);
    o00.z = zc0.z + 0.3f * (h00[2] + cb0.z); o00.w = zc0.w + 0.3f * (h00[3] + cb0.w);
    o01.x = zc0.x + 0.3f * (h01[0] + cb0.x); o01.y = zc0.y + 0.3f * (h01[1] + cb0.y);
    o01.z = zc0.z + 0.3f * (h01[2] + cb0.z); o01.w = zc0.w + 0.3f * (h01[3] + cb0.w);
    o10.x = zc1.x + 0.3f * (h10[0] + cb1.x); o10.y = zc1.y + 0.3f * (h10[1] + cb1.y);
    o10.z = zc1.z + 0.3f * (h10[2] + cb1.z); o10.w = zc1.w + 0.3f * (h10[3] + cb1.w);
    o11.x = zc1.x + 0.3f * (h11[0] + cb1.x); o11.y = zc1.y + 0.3f * (h11[1] + cb1.y);
    o11.z = zc1.z + 0.3f * (h11[2] + cb1.z); o11.w = zc1.w + 0.3f * (h11[3] + cb1.w);
    *(float4*)&out[ob + ((long)l15 << 8) + oc0] = o00;
    *(float4*)&out[ob + ((long)(16 + l15) << 8) + oc0] = o01;
    *(float4*)&out[ob + ((long)l15 << 8) + oc1] = o10;
    *(float4*)&out[ob + ((long)(16 + l15) << 8) + oc1] = o11;
}

extern "C" void kernel_launch(void* const* d_in, const int* in_sizes, int n_in,
                              void* d_out, int out_size, void* d_ws, size_t ws_size,
                              hipStream_t stream) {
    const float* x = (const float*)d_in[0];
    const float* in_proj_w = (const float*)d_in[1];
    const float* in_proj_b = (const float*)d_in[2];
    const float* pe_w1 = (const float*)d_in[3];
    const float* pe_b1 = (const float*)d_in[4];
    const float* pe_w2 = (const float*)d_in[5];
    const float* pe_b2 = (const float*)d_in[6];
    const float* noise_w = (const float*)d_in[7];
    const float* noise_b = (const float*)d_in[8];
    const float* sfe_w1 = (const float*)d_in[9];
    const float* sfe_b1 = (const float*)d_in[10];
    const float* sfe_w2 = (const float*)d_in[11];
    const float* sfe_b2 = (const float*)d_in[12];
    const float* comb_w1 = (const float*)d_in[13];
    const float* comb_b1 = (const float*)d_in[14];
    const float* comb_w2 = (const float*)d_in[15];
    const float* comb_b2 = (const float*)d_in[16];
    const float* pool_param = (const float*)d_in[17];
    float* ws = (float*)d_ws;
    float* out = (float*)d_out;

    hipLaunchKernelGGL(k_A, dim3(2040), dim3(256), 0, stream,
                       x, in_proj_w, sfe_w1, sfe_w2, sfe_b2, comb_w1, comb_w2, ws);
    hipLaunchKernelGGL(k_B, dim3(200), dim3(128), 0, stream,
                       pool_param, pe_w1, pe_b1, pe_w2, pe_b2, noise_w, noise_b, in_proj_b, ws);
    hipLaunchKernelGGL(k_C, dim3(21), dim3(256), 0, stream, in_proj_b, ws, out);
    hipLaunchKernelGGL(k_D, dim3(616), dim3(256), 0, stream, sfe_w1, sfe_b1, ws);
    hipLaunchKernelGGL(k_final1, dim3(32, 8, 2), dim3(512), 0, stream,
                       ws, (const ushort_t*)(ws + OFF_XC), (const ushort_t*)(ws + OFF_AB),
                       ws + OFF_PACC);
    hipLaunchKernelGGL(k_final2, dim3(32, 8), dim3(512), 0, stream,
                       ws, ws + OFF_PACC, comb_b1, comb_b2, out);
}